// Round 9
// baseline (318.567 us; speedup 1.0000x reference)
//
#include <hip/hip_runtime.h>
#include <math.h>

#define HIDDEN   1024
#define D_INNER  2048
#define NSTATE   16
#define DT_RANK  64
#define BATCH    2
#define SEQ      2048
#define T_TOK    (BATCH * SEQ)            /* 4096 tokens */
#define XDBL     (DT_RANK + 2 * NSTATE)   /* 96 */
#define NCH      64                       /* scan chunks */
#define CHL      (SEQ / NCH)              /* 32 steps per chunk */
#define BDN      (BATCH * D_INNER * NSTATE) /* 65536 */

typedef float f32x4   __attribute__((ext_vector_type(4)));
typedef short bf16x8  __attribute__((ext_vector_type(8)));
typedef short short4v __attribute__((ext_vector_type(4)));

#define AS1 __attribute__((address_space(1)))
#define AS3 __attribute__((address_space(3)))
#define GLOAD(src, dst) __builtin_amdgcn_global_load_lds( \
    (const AS1 unsigned int*)(src), (AS3 unsigned int*)(dst), 16, 0, 0)

__device__ __forceinline__ float silu_f(float x) { return x / (1.0f + __expf(-x)); }
__device__ __forceinline__ float softplus_f(float x) {
    return fmaxf(x, 0.0f) + log1pf(__expf(-fabsf(x)));
}
__device__ __forceinline__ unsigned short f2bf(float x) {
    unsigned int u = __float_as_uint(x);
    u += 0x7fffu + ((u >> 16) & 1u);           /* RNE */
    return (unsigned short)(u >> 16);
}
__device__ __forceinline__ float bf2f(unsigned short h) {
    return __uint_as_float(((unsigned int)h) << 16);
}

/* ---- weight pack. MODE 0: [hi|lo] (2K). MODE 1: [hi|hi] (2K). MODE 2: [hi|lo|hi] (3K). ---- */
template<int MODE>
__global__ __launch_bounds__(256) void wpack_kernel(
        const float* __restrict__ w, unsigned short* __restrict__ wp, int K) {
    int i = blockIdx.x * 256 + threadIdx.x;
    int kq = K >> 2;
    int row = i / kq;
    int c = (i - row * kq) << 2;
    float4 v = *(const float4*)(w + (size_t)row * K + c);
    short4v hi, lo;
    hi.x = f2bf(v.x); hi.y = f2bf(v.y); hi.z = f2bf(v.z); hi.w = f2bf(v.w);
    lo.x = f2bf(v.x - bf2f(hi.x)); lo.y = f2bf(v.y - bf2f(hi.y));
    lo.z = f2bf(v.z - bf2f(hi.z)); lo.w = f2bf(v.w - bf2f(hi.w));
    size_t b0 = (size_t)row * ((MODE == 2 ? 3 : 2) * K) + c;
    if (MODE == 0) {
        *(short4v*)(wp + b0)     = hi;
        *(short4v*)(wp + b0 + K) = lo;
    } else if (MODE == 1) {
        *(short4v*)(wp + b0)     = hi;
        *(short4v*)(wp + b0 + K) = hi;
    } else {
        *(short4v*)(wp + b0)         = hi;
        *(short4v*)(wp + b0 + K)     = lo;
        *(short4v*)(wp + b0 + 2 * K) = hi;
    }
}

/* ---- RMSNorm + [hi|lo] act pack: x[row,1024] -> xn_p[row,2048] ---- */
__global__ __launch_bounds__(256) void rmsnorm_pack_kernel(
        const float* __restrict__ x, const float* __restrict__ w,
        unsigned short* __restrict__ xn_p) {
    int row = blockIdx.x;
    float4 v = ((const float4*)(x + (size_t)row * HIDDEN))[threadIdx.x];
    float ss = v.x*v.x + v.y*v.y + v.z*v.z + v.w*v.w;
    #pragma unroll
    for (int off = 32; off; off >>= 1) ss += __shfl_down(ss, off);
    __shared__ float wsum[4];
    if ((threadIdx.x & 63) == 0) wsum[threadIdx.x >> 6] = ss;
    __syncthreads();
    float scale = rsqrtf((wsum[0] + wsum[1] + wsum[2] + wsum[3]) / (float)HIDDEN + 1e-5f);
    float4 wv = ((const float4*)w)[threadIdx.x];
    float o0 = v.x * scale * wv.x, o1 = v.y * scale * wv.y;
    float o2 = v.z * scale * wv.z, o3 = v.w * scale * wv.w;
    short4v hi, lo;
    hi.x = f2bf(o0); hi.y = f2bf(o1); hi.z = f2bf(o2); hi.w = f2bf(o3);
    lo.x = f2bf(o0 - bf2f(hi.x)); lo.y = f2bf(o1 - bf2f(hi.y));
    lo.z = f2bf(o2 - bf2f(hi.z)); lo.w = f2bf(o3 - bf2f(hi.w));
    size_t b0 = (size_t)row * (2 * HIDDEN) + threadIdx.x * 4;
    *(short4v*)&xn_p[b0]          = hi;
    *(short4v*)&xn_p[b0 + HIDDEN] = lo;
}

/* ==== 8-phase 256x256 bf16 GEMM (T3+T4+T5), 512 thr, 128 KiB LDS ====
   C[M,N] = Ap[M,Kp] @ Wp[N,Kp]^T over k in [z*klen, (z+1)*klen)
   EPI 0: block cols < D_INNER -> C0 else C1 (ldout stride both)
   EPI 2: partial store to C0 + z*partStride
   Schedule per K-tile (4 phases): ds-reads + front-loaded prefetch of
   tile t+1 (phases 0-1), raw barriers, setprio around MFMA, single
   vmcnt(0) per tile after the last MFMA (never mid-phase).             */
template<int EPI>
__global__ __launch_bounds__(512, 2) void mgemm8_kernel(
        const unsigned short* __restrict__ Ap, const unsigned short* __restrict__ Wp,
        int Kp, int klen, float* __restrict__ C0, float* __restrict__ C1,
        int ldout, size_t partStride) {
    __shared__ short lds8[65536];   /* bytes: A 4x16KB at 0, B 4x16KB at 65536 */
    const int t = threadIdx.x;
    const int w = t >> 6, l = t & 63;
    const int wm = w >> 2, wn = w & 3;
    const int m0 = blockIdx.y * 256, n0 = blockIdx.x * 256;
    const int kbeg = blockIdx.z * klen;
    const int NT = klen >> 6;
    const int lrow = l & 15;
    const int sl0 = (((l >> 4)    ) ^ (l & 7)) * 8;   /* kk=0 swizzled slot */
    const int sl1 = (((l >> 4) + 4) ^ (l & 7)) * 8;   /* kk=1 */
    f32x4 acc[8][4];
    #pragma unroll
    for (int m = 0; m < 8; ++m)
        #pragma unroll
        for (int n = 0; n < 4; ++n) {
            acc[m][n].x = 0.f; acc[m][n].y = 0.f; acc[m][n].z = 0.f; acc[m][n].w = 0.f;
        }
    const int srow8 = l >> 3;
    const int sc8   = (l & 7) ^ srow8;
    const unsigned short* gA = Ap + (size_t)(m0 + w * 8 + srow8) * Kp + kbeg + sc8 * 8;
    const unsigned short* gB = Wp + (size_t)(n0 + w * 8 + srow8) * Kp + kbeg + sc8 * 8;
    /* stage one 256x64 tile (A or B) into buf c: 4 gloads, hq = half*2+q */
    auto stageA = [&](int c, int koff) {
        #pragma unroll
        for (int hq = 0; hq < 4; ++hq)
            GLOAD(gA + (size_t)(hq * 64) * Kp + koff,
                  (char*)lds8 + ((c * 2 + (hq >> 1)) * 16384)
                              + ((hq & 1) * 64 + w * 8) * 128);
    };
    auto stageB = [&](int c, int koff) {
        #pragma unroll
        for (int hq = 0; hq < 4; ++hq)
            GLOAD(gB + (size_t)(hq * 64) * Kp + koff,
                  (char*)lds8 + 65536 + ((c * 2 + (hq >> 1)) * 16384)
                              + ((hq & 1) * 64 + w * 8) * 128);
    };
    /* prologue: stage tile 0 into buf 0 */
    stageA(0, 0);
    stageB(0, 0);
    asm volatile("s_waitcnt vmcnt(0)" ::: "memory");
    __builtin_amdgcn_s_barrier();
    for (int tt = 0; tt < NT; ++tt) {
        const int c = tt & 1;
        const int knext = (tt + 1) * 64;
        const bool more = (tt + 1 < NT);
        const short* Ab = lds8 + (c * 2 + wm) * 8192;            /* shorts */
        const short* Bb = lds8 + 32768 + (c * 2 + (wn >> 1)) * 8192;
        const int br0 = (wn & 1) * 64;
        bf16x8 bh[4], af[4];
        /* ---- phase 0: kk=0, m0-3 ; prefetch A(t+1) ---- */
        #pragma unroll
        for (int n = 0; n < 4; ++n)
            bh[n] = *(const bf16x8*)&Bb[(br0 + n * 16 + lrow) * 64 + sl0];
        #pragma unroll
        for (int m = 0; m < 4; ++m)
            af[m] = *(const bf16x8*)&Ab[(m * 16 + lrow) * 64 + sl0];
        if (more) stageA(c ^ 1, knext);
        __builtin_amdgcn_s_barrier();
        asm volatile("s_waitcnt lgkmcnt(0)" ::: "memory");
        __builtin_amdgcn_s_setprio(1);
        #pragma unroll
        for (int m = 0; m < 4; ++m)
            #pragma unroll
            for (int n = 0; n < 4; ++n)
                acc[m][n] = __builtin_amdgcn_mfma_f32_16x16x32_bf16(
                    af[m], bh[n], acc[m][n], 0, 0, 0);
        __builtin_amdgcn_s_setprio(0);
        __builtin_amdgcn_s_barrier();
        /* ---- phase 1: kk=0, m4-7 ; prefetch B(t+1) ---- */
        #pragma unroll
        for (int m = 0; m < 4; ++m)
            af[m] = *(const bf16x8*)&Ab[((m + 4) * 16 + lrow) * 64 + sl0];
        if (more) stageB(c ^ 1, knext);
        __builtin_amdgcn_s_barrier();
        asm volatile("s_waitcnt lgkmcnt(0)" ::: "memory");
        __builtin_amdgcn_s_setprio(1);
        #pragma unroll
        for (int m = 0; m < 4; ++m)
            #pragma unroll
            for (int n = 0; n < 4; ++n)
                acc[m + 4][n] = __builtin_amdgcn_mfma_f32_16x16x32_bf16(
                    af[m], bh[n], acc[m + 4][n], 0, 0, 0);
        __builtin_amdgcn_s_setprio(0);
        __builtin_amdgcn_s_barrier();
        /* ---- phase 2: kk=1, m0-3 ---- */
        #pragma unroll
        for (int n = 0; n < 4; ++n)
            bh[n] = *(const bf16x8*)&Bb[(br0 + n * 16 + lrow) * 64 + sl1];
        #pragma unroll
        for (int m = 0; m < 4; ++m)
            af[m] = *(const bf16x8*)&Ab[(m * 16 + lrow) * 64 + sl1];
        __builtin_amdgcn_s_barrier();
        asm volatile("s_waitcnt lgkmcnt(0)" ::: "memory");
        __builtin_amdgcn_s_setprio(1);
        #pragma unroll
        for (int m = 0; m < 4; ++m)
            #pragma unroll
            for (int n = 0; n < 4; ++n)
                acc[m][n] = __builtin_amdgcn_mfma_f32_16x16x32_bf16(
                    af[m], bh[n], acc[m][n], 0, 0, 0);
        __builtin_amdgcn_s_setprio(0);
        __builtin_amdgcn_s_barrier();
        /* ---- phase 3: kk=1, m4-7 ; tile-boundary vmcnt ---- */
        #pragma unroll
        for (int m = 0; m < 4; ++m)
            af[m] = *(const bf16x8*)&Ab[((m + 4) * 16 + lrow) * 64 + sl1];
        __builtin_amdgcn_s_barrier();
        asm volatile("s_waitcnt lgkmcnt(0)" ::: "memory");
        __builtin_amdgcn_s_setprio(1);
        #pragma unroll
        for (int m = 0; m < 4; ++m)
            #pragma unroll
            for (int n = 0; n < 4; ++n)
                acc[m + 4][n] = __builtin_amdgcn_mfma_f32_16x16x32_bf16(
                    af[m], bh[n], acc[m + 4][n], 0, 0, 0);
        __builtin_amdgcn_s_setprio(0);
        asm volatile("s_waitcnt vmcnt(0)" ::: "memory");   /* t+1 staged & landed */
        __builtin_amdgcn_s_barrier();
    }
    /* epilogue */
    float* dstp = (EPI == 2) ? (C0 + blockIdx.z * partStride)
                             : ((n0 < D_INNER) ? C0 : C1);
    const int cb = (EPI == 0 && n0 >= D_INNER) ? D_INNER : 0;
    #pragma unroll
    for (int m = 0; m < 8; ++m) {
        #pragma unroll
        for (int n = 0; n < 4; ++n) {
            #pragma unroll
            for (int j = 0; j < 4; ++j) {
                int row = m0 + wm * 128 + m * 16 + (l >> 4) * 4 + j;
                int col = n0 + wn * 64 + n * 16 + (l & 15);
                dstp[(size_t)row * ldout + (col - cb)] = acc[m][n][j];
            }
        }
    }
}

/* ---- component-packed split-bf16 MFMA GEMM (128x128) — x_proj / dt_proj ----
   TERMS=3: C = Ah·Wh + Ah·Wl + Al·Wh  (A [hi|lo] stride 2K, W [hi|lo] stride 2K)
   EPI 2: partial store to C0 + z*partStride
   EPI 3: softplus(v + bias[col]) -> C0                                   */
template<int TERMS, int EPI>
__global__ __launch_bounds__(256) void mgemm_kernel(
        const unsigned short* __restrict__ Ap, const unsigned short* __restrict__ Wp,
        int Klog, int klen, int brows, float* __restrict__ C0, float* __restrict__ C1,
        int splitN, int ldout, size_t partStride, const float* __restrict__ bias) {
    constexpr int NT = (TERMS == 3) ? 4 : 3;
    __shared__ short lds[NT * 128 * 64];
    short* Ah = lds;
    short* Al = lds + 128 * 64;
    short* Bh = lds + 2 * 128 * 64;
    short* Bl = lds + 3 * 128 * 64;
    const int t = threadIdx.x;
    const int w = t >> 6, l = t & 63;
    const int m0 = blockIdx.y * 128, n0 = blockIdx.x * 128;
    const int kbeg = blockIdx.z * klen;
    const int wr = (w >> 1) * 64, wc = (w & 1) * 64;
    const int lrow = l & 15;
    f32x4 acc[4][4];
    #pragma unroll
    for (int m = 0; m < 4; ++m)
        #pragma unroll
        for (int n = 0; n < 4; ++n) {
            acc[m][n].x = 0.f; acc[m][n].y = 0.f; acc[m][n].z = 0.f; acc[m][n].w = 0.f;
        }
    const int Asr = 2 * Klog;
    const int Wsr = (TERMS == 3) ? 2 * Klog : Klog;
    const int srow = w * 32 + (l >> 3);
    const int sc8  = (l & 7) ^ ((l >> 3) & 7);
    const int brow = min(n0 + srow, brows - 1);   /* clamp for padded-N */
    const unsigned short* ga = Ap + (size_t)(m0 + srow) * Asr + sc8 * 8;
    const unsigned short* gb = Wp + (size_t)brow * Wsr + sc8 * 8;
    for (int k0 = kbeg; k0 < kbeg + klen; k0 += 64) {
        __syncthreads();
        #pragma unroll
        for (int q = 0; q < 4; ++q) {
            const int doff = (w * 32 + q * 8) * 128;
            GLOAD(ga + k0 + (size_t)q * 8 * Asr,        (char*)Ah + doff);
            GLOAD(ga + Klog + k0 + (size_t)q * 8 * Asr, (char*)Al + doff);
            GLOAD(gb + k0 + (size_t)q * 8 * Wsr,        (char*)Bh + doff);
            if (TERMS == 3)
                GLOAD(gb + Klog + k0 + (size_t)q * 8 * Wsr, (char*)Bl + doff);
        }
        __syncthreads();
        #pragma unroll
        for (int kk = 0; kk < 2; ++kk) {
            const int slot = ((kk * 4 + (l >> 4)) ^ (l & 7)) * 8;
            bf16x8 ah[4], al[4], bh[4], bl[4];
            #pragma unroll
            for (int m = 0; m < 4; ++m) {
                ah[m] = *(const bf16x8*)&Ah[(wr + m * 16 + lrow) * 64 + slot];
                al[m] = *(const bf16x8*)&Al[(wr + m * 16 + lrow) * 64 + slot];
            }
            #pragma unroll
            for (int n = 0; n < 4; ++n) {
                bh[n] = *(const bf16x8*)&Bh[(wc + n * 16 + lrow) * 64 + slot];
                if (TERMS == 3)
                    bl[n] = *(const bf16x8*)&Bl[(wc + n * 16 + lrow) * 64 + slot];
            }
            #pragma unroll
            for (int m = 0; m < 4; ++m)
                #pragma unroll
                for (int n = 0; n < 4; ++n) {
                    acc[m][n] = __builtin_amdgcn_mfma_f32_16x16x32_bf16(
                        ah[m], bh[n], acc[m][n], 0, 0, 0);
                    acc[m][n] = __builtin_amdgcn_mfma_f32_16x16x32_bf16(
                        al[m], bh[n], acc[m][n], 0, 0, 0);
                    if (TERMS == 3)
                        acc[m][n] = __builtin_amdgcn_mfma_f32_16x16x32_bf16(
                            ah[m], bl[n], acc[m][n], 0, 0, 0);
                }
        }
    }
    float* dst = (EPI == 2) ? (C0 + blockIdx.z * partStride) : C0;
    #pragma unroll
    for (int m = 0; m < 4; ++m) {
        #pragma unroll
        for (int n = 0; n < 4; ++n) {
            #pragma unroll
            for (int j = 0; j < 4; ++j) {
                int row = m0 + wr + m * 16 + (l >> 4) * 4 + j;
                int col = n0 + wc + n * 16 + (l & 15);
                float v = acc[m][n][j];
                if (EPI == 2) {
                    dst[(size_t)row * ldout + col] = v;
                } else {
                    C0[(size_t)row * ldout + col] = softplus_f(v + bias[col]);
                }
            }
        }
    }
}

/* ---- reduce 4 split-K partials + residual x -> out (out_proj) ---- */
__global__ __launch_bounds__(256) void reduce4_kernel(
        const float* __restrict__ parts, size_t partStride,
        const float* __restrict__ x, float* __restrict__ out) {
    size_t i = (size_t)blockIdx.x * 256 + threadIdx.x;   /* float4 index */
    float4 a = ((const float4*)(parts))[i];
    float4 b = ((const float4*)(parts + partStride))[i];
    float4 c = ((const float4*)(parts + 2 * partStride))[i];
    float4 d = ((const float4*)(parts + 3 * partStride))[i];
    float4 xv = ((const float4*)x)[i];
    float4 o;
    o.x = a.x + b.x + c.x + d.x + xv.x;
    o.y = a.y + b.y + c.y + d.y + xv.y;
    o.z = a.z + b.z + c.z + d.z + xv.z;
    o.w = a.w + b.w + c.w + d.w + xv.w;
    ((float4*)out)[i] = o;
}

/* ---- reduce 8 x_proj partials -> xdbl fp32 [4096,96] + dtp_p [hi|lo] [4096,128] ---- */
__global__ __launch_bounds__(256) void reduceX_kernel(
        const float* __restrict__ parts, float* __restrict__ xdbl,
        unsigned short* __restrict__ dtp) {
    int i = blockIdx.x * 256 + threadIdx.x;      /* 4096*24 total */
    int row = i / 24;
    int c = (i - row * 24) * 4;
    float4 s = make_float4(0.f, 0.f, 0.f, 0.f);
    #pragma unroll
    for (int z = 0; z < 8; ++z) {
        float4 a = *(const float4*)(parts + (size_t)z * 524288 + (size_t)row * 128 + c);
        s.x += a.x; s.y += a.y; s.z += a.z; s.w += a.w;
    }
    *(float4*)(xdbl + (size_t)row * XDBL + c) = s;
    if (c < DT_RANK) {
        short4v hi, lo;
        hi.x = f2bf(s.x); hi.y = f2bf(s.y); hi.z = f2bf(s.z); hi.w = f2bf(s.w);
        lo.x = f2bf(s.x - bf2f(hi.x)); lo.y = f2bf(s.y - bf2f(hi.y));
        lo.z = f2bf(s.z - bf2f(hi.z)); lo.w = f2bf(s.w - bf2f(hi.w));
        size_t b0 = (size_t)row * 128 + c;
        *(short4v*)(dtp + b0)      = hi;
        *(short4v*)(dtp + b0 + 64) = lo;
    }
}

/* ---- causal depthwise conv (d_conv=4) + SiLU -> [hi|lo] packed xc ---- */
__global__ __launch_bounds__(256) void conv_silu_kernel(
        const float* __restrict__ xi, const float* __restrict__ w,
        const float* __restrict__ b, unsigned short* __restrict__ xc_p) {
    size_t i = (size_t)blockIdx.x * 256 + threadIdx.x;
    int d = (int)(i & (D_INNER - 1));
    int tt = (int)(i >> 11);
    int s = tt & (SEQ - 1);
    float4 wv = ((const float4*)w)[d];
    float acc = b[d];
    if (s >= 3) acc += wv.x * xi[i - 3 * D_INNER];
    if (s >= 2) acc += wv.y * xi[i - 2 * D_INNER];
    if (s >= 1) acc += wv.z * xi[i - 1 * D_INNER];
    acc += wv.w * xi[i];
    float o = silu_f(acc);
    unsigned short hi = f2bf(o);
    unsigned short lo = f2bf(o - bf2f(hi));
    size_t o2 = (size_t)tt * (2 * D_INNER) + d;
    xc_p[o2]           = hi;
    xc_p[o2 + D_INNER] = lo;
}

/* ==== selective scan: thread-per-(b,d,chunk), states in registers ==== */

__global__ __launch_bounds__(256) void scanA_kernel(
        const unsigned short* __restrict__ xcp, const float* __restrict__ delta,
        const float* __restrict__ xdbl, const float* __restrict__ A_log,
        float* __restrict__ hpart, float* __restrict__ Pp) {
    const int bid = blockIdx.x;            /* 1024 blocks */
    const int b    = bid >> 9;
    const int c    = (bid >> 3) & 63;
    const int dblk = bid & 7;
    const int d    = (dblk << 8) + threadIdx.x;
    float adn[NSTATE];
    #pragma unroll
    for (int k = 0; k < 4; ++k) {
        float4 a = *(const float4*)(A_log + d * NSTATE + k * 4);
        adn[k*4+0] = -__expf(a.x); adn[k*4+1] = -__expf(a.y);
        adn[k*4+2] = -__expf(a.z); adn[k*4+3] = -__expf(a.w);
    }
    float h[NSTATE], P[NSTATE];
    #pragma unroll
    for (int n = 0; n < NSTATE; ++n) { h[n] = 0.f; P[n] = 1.f; }
    const int rowbase = b * SEQ + c * CHL;
    #pragma unroll 4
    for (int r = 0; r < CHL; ++r) {
        const int row = rowbase + r;
        const float* brow = xdbl + (size_t)row * XDBL + DT_RANK;  /* uniform addr */
        size_t o2 = (size_t)row * (2 * D_INNER) + d;
        float dl = delta[(size_t)row * D_INNER + d];
        float u  = bf2f(xcp[o2]) + bf2f(xcp[o2 + D_INNER]);
        float du = dl * u;
        #pragma unroll
        for (int n = 0; n < NSTATE; ++n) {
            float dA = __expf(dl * adn[n]);
            h[n] = fmaf(dA, h[n], du * brow[n]);
            P[n] *= dA;
        }
    }
    size_t base = (size_t)c * BDN + (size_t)(b * D_INNER + d) * NSTATE;
    #pragma unroll
    for (int k = 0; k < 4; ++k) {
        *(float4*)(hpart + base + k * 4) = make_float4(h[k*4], h[k*4+1], h[k*4+2], h[k*4+3]);
        *(float4*)(Pp    + base + k * 4) = make_float4(P[k*4], P[k*4+1], P[k*4+2], P[k*4+3]);
    }
}

__global__ __launch_bounds__(256) void scanB_kernel(
        const float* __restrict__ hpart, const float* __restrict__ Pp,
        float* __restrict__ hstart) {
    int idx = blockIdx.x * 256 + threadIdx.x;
    float h = 0.f;
    for (int c = 0; c < NCH; ++c) {
        hstart[(size_t)c * BDN + idx] = h;
        h = fmaf(Pp[(size_t)c * BDN + idx], h, hpart[(size_t)c * BDN + idx]);
    }
}

/* scanC: writes y as [hi|hi|lo] (stride 3*D_INNER) for the 8-phase out_proj. */
__global__ __launch_bounds__(256) void scanC_kernel(
        const unsigned short* __restrict__ xcp, const float* __restrict__ delta,
        const float* __restrict__ xdbl, const float* __restrict__ A_log,
        const float* __restrict__ Dp, const float* __restrict__ hstart,
        const float* __restrict__ res, unsigned short* __restrict__ y_p) {
    const int bid = blockIdx.x;            /* 1024 blocks */
    const int b    = bid >> 9;
    const int c    = (bid >> 3) & 63;
    const int dblk = bid & 7;
    const int d    = (dblk << 8) + threadIdx.x;
    float adn[NSTATE];
    #pragma unroll
    for (int k = 0; k < 4; ++k) {
        float4 a = *(const float4*)(A_log + d * NSTATE + k * 4);
        adn[k*4+0] = -__expf(a.x); adn[k*4+1] = -__expf(a.y);
        adn[k*4+2] = -__expf(a.z); adn[k*4+3] = -__expf(a.w);
    }
    const float Dd = Dp[d];
    float h[NSTATE];
    size_t base = (size_t)c * BDN + (size_t)(b * D_INNER + d) * NSTATE;
    #pragma unroll
    for (int k = 0; k < 4; ++k) {
        float4 hv = *(const float4*)(hstart + base + k * 4);
        h[k*4] = hv.x; h[k*4+1] = hv.y; h[k*4+2] = hv.z; h[k*4+3] = hv.w;
    }
    const int rowbase = b * SEQ + c * CHL;
    #pragma unroll 4
    for (int r = 0; r < CHL; ++r) {
        const int row = rowbase + r;
        const float* brow = xdbl + (size_t)row * XDBL + DT_RANK;       /* uniform */
        const float* crow = brow + NSTATE;                              /* uniform */
        size_t o2 = (size_t)row * (2 * D_INNER) + d;
        float dl = delta[(size_t)row * D_INNER + d];
        float u  = bf2f(xcp[o2]) + bf2f(xcp[o2 + D_INNER]);
        float du = dl * u;
        float ys[4];
        ys[0] = u * Dd; ys[1] = 0.f; ys[2] = 0.f; ys[3] = 0.f;
        #pragma unroll
        for (int n = 0; n < NSTATE; ++n) {
            float dA = __expf(dl * adn[n]);
            h[n] = fmaf(dA, h[n], du * brow[n]);
            ys[n & 3] = fmaf(h[n], crow[n], ys[n & 3]);
        }
        float ysum = (ys[0] + ys[1]) + (ys[2] + ys[3]);
        float rv = res[(size_t)row * D_INNER + d];
        float gv = ysum * silu_f(rv);
        unsigned short hi = f2bf(gv);
        unsigned short lo = f2bf(gv - bf2f(hi));
        size_t o6 = (size_t)row * (3 * D_INNER) + d;
        y_p[o6]                = hi;
        y_p[o6 + D_INNER]      = hi;
        y_p[o6 + 2 * D_INNER]  = lo;
    }
}

extern "C" void kernel_launch(void* const* d_in, const int* in_sizes, int n_in,
                              void* d_out, int out_size, void* d_ws, size_t ws_size,
                              hipStream_t stream) {
    const float* x         = (const float*)d_in[0];
    const float* norm_w    = (const float*)d_in[1];
    const float* in_proj_w = (const float*)d_in[2];
    const float* conv_w    = (const float*)d_in[3];
    const float* conv_b    = (const float*)d_in[4];
    const float* x_proj_w  = (const float*)d_in[5];
    const float* dt_proj_w = (const float*)d_in[6];
    const float* dt_proj_b = (const float*)d_in[7];
    const float* A_log     = (const float*)d_in[8];
    const float* Dp        = (const float*)d_in[9];
    const float* out_proj_w= (const float*)d_in[10];
    float* out = (float*)d_out;
    float* ws  = (float*)d_ws;

    const size_t M8 = (size_t)T_TOK * D_INNER;            /* 8388608 */
    /* layout (float units):
       [0, 8M)        res           (live until scanC)
       [8M, 16M)      delta         (parts_x aliases pre-dt_proj)
       [16M, +393216) xdbl
       block16 (16M fl, contiguous; all dead after conv):
         xn_p (4M fl), w_in_p (4M fl), xi (8M fl); y_p (12M fl) aliases it
       w_out_p 3M | w_xp_p 0.1875M | w_dt_p 0.125M | xc_p 8M | dtp_p 0.25M
       hpart 4M | Pp 4M | hstart 4M
       parts (16.78M) aliases xc_p.. (all dead after scanC)             */
    float* res   = ws;
    float* delta = ws + M8;
    float* xdbl  = ws + 2 * M8;
    size_t off = 2 * M8 + 393216;
    unsigned short* xn_p   = (unsigned short*)(ws + off);
    unsigned short* w_in_p = xn_p + (size_t)4096 * 2048;
    float* xi = ws + off + 8388608;
    unsigned short* y_p = xn_p;                       /* 4096x6144 sh = 12M fl */
    size_t off2 = off + 16777216;
    unsigned short* w_out_p = (unsigned short*)(ws + off2);      /* 1024x6144 sh */
    size_t off3 = off2 + 3145728;
    unsigned short* w_xp_p = (unsigned short*)(ws + off3);       /* 96x4096 sh */
    size_t off4 = off3 + 196608;
    unsigned short* w_dt_p = (unsigned short*)(ws + off4);       /* 2048x128 sh */
    size_t off5 = off4 + 131072;
    unsigned short* xc_p = (unsigned short*)(ws + off5);         /* 4096x4096 sh */
    size_t off6 = off5 + 8388608;
    unsigned short* dtp_p = (unsigned short*)(ws + off6);        /* 4096x128 sh */
    size_t off7 = off6 + 262144;
    float* hpart  = ws + off7;
    float* Pp     = hpart + 4194304;
    float* hstart = Pp + 4194304;
    float* parts_x = delta;
    float* parts   = ws + off5;                       /* spans xc_p..Pp (dead) */
    const size_t partStride = (size_t)T_TOK * HIDDEN;            /* 4194304 */

    /* weight packs */
    wpack_kernel<1><<<4096, 256, 0, stream>>>(in_proj_w,  w_in_p,  HIDDEN);   /* [hi|hi] */
    wpack_kernel<2><<<2048, 256, 0, stream>>>(out_proj_w, w_out_p, D_INNER);  /* [hi|lo|hi] */
    wpack_kernel<0><<<192,  256, 0, stream>>>(x_proj_w,   w_xp_p,  D_INNER);  /* [hi|lo] */
    wpack_kernel<0><<<128,  256, 0, stream>>>(dt_proj_w,  w_dt_p,  DT_RANK);  /* [hi|lo] */

    /* RMSNorm + [hi|lo] pack */
    rmsnorm_pack_kernel<<<T_TOK, 256, 0, stream>>>(x, norm_w, xn_p);

    { /* in_proj (8-phase, Kp=2048 = 2-term): -> xi | res */
        dim3 g(4096 / 256, T_TOK / 256, 1);
        mgemm8_kernel<0><<<g, 512, 0, stream>>>(xn_p, w_in_p, 2 * HIDDEN, 2 * HIDDEN,
                                                xi, res, D_INNER, 0);
    }

    /* conv + SiLU -> [hi|lo] packed xc */
    conv_silu_kernel<<<(int)(M8 / 256), 256, 0, stream>>>(xi, conv_w, conv_b, xc_p);

    { /* x_proj (3-term, split-K=8, N padded 96->128): partials */
        dim3 g(1, T_TOK / 128, 8);
        mgemm_kernel<3, 2><<<g, 256, 0, stream>>>(xc_p, w_xp_p, D_INNER, D_INNER / 8,
                                                  96, parts_x, nullptr, 0, 128, 524288, nullptr);
    }
    reduceX_kernel<<<T_TOK * 24 / 256, 256, 0, stream>>>(parts_x, xdbl, dtp_p);

    { /* dt_proj (3-term) + bias + softplus -> delta */
        dim3 g(D_INNER / 128, T_TOK / 128, 1);
        mgemm_kernel<3, 3><<<g, 256, 0, stream>>>(dtp_p, w_dt_p, DT_RANK, DT_RANK,
                                                  D_INNER, delta, nullptr, 0, D_INNER, 0, dt_proj_b);
    }

    /* selective scan */
    scanA_kernel<<<BATCH * NCH * 8, 256, 0, stream>>>(xc_p, delta, xdbl, A_log, hpart, Pp);
    scanB_kernel<<<BDN / 256, 256, 0, stream>>>(hpart, Pp, hstart);
    scanC_kernel<<<BATCH * NCH * 8, 256, 0, stream>>>(xc_p, delta, xdbl, A_log, Dp, hstart, res, y_p);

    { /* out_proj (8-phase, Kp=6144 = 3-term, split-K=4): partials */
        dim3 g(HIDDEN / 256, T_TOK / 256, 4);
        mgemm8_kernel<2><<<g, 512, 0, stream>>>(y_p, w_out_p, 3 * D_INNER, 6144 / 4,
                                                parts, nullptr, HIDDEN, partStride);
    }
    /* residual + reduce */
    reduce4_kernel<<<(int)(partStride / 4 / 256), 256, 0, stream>>>(parts, partStride, x, out);
}

// Round 10
// 303.829 us; speedup vs baseline: 1.0485x; 1.0485x over previous
//
#include <hip/hip_runtime.h>
#include <math.h>

#define HIDDEN   1024
#define D_INNER  2048
#define NSTATE   16
#define DT_RANK  64
#define BATCH    2
#define SEQ      2048
#define T_TOK    (BATCH * SEQ)            /* 4096 tokens */
#define XDBL     (DT_RANK + 2 * NSTATE)   /* 96 */
#define NCH      64                       /* scan chunks */
#define CHL      (SEQ / NCH)              /* 32 steps per chunk */
#define BDN      (BATCH * D_INNER * NSTATE) /* 65536 */

typedef float f32x4   __attribute__((ext_vector_type(4)));
typedef short bf16x8  __attribute__((ext_vector_type(8)));
typedef short short4v __attribute__((ext_vector_type(4)));

#define AS1 __attribute__((address_space(1)))
#define AS3 __attribute__((address_space(3)))
#define GLOAD(src, dst) __builtin_amdgcn_global_load_lds( \
    (const AS1 unsigned int*)(src), (AS3 unsigned int*)(dst), 16, 0, 0)

__device__ __forceinline__ float silu_f(float x) { return x / (1.0f + __expf(-x)); }
__device__ __forceinline__ float softplus_f(float x) {
    return fmaxf(x, 0.0f) + log1pf(__expf(-fabsf(x)));
}
__device__ __forceinline__ unsigned short f2bf(float x) {
    unsigned int u = __float_as_uint(x);
    u += 0x7fffu + ((u >> 16) & 1u);           /* RNE */
    return (unsigned short)(u >> 16);
}
__device__ __forceinline__ float bf2f(unsigned short h) {
    return __uint_as_float(((unsigned int)h) << 16);
}

/* ---- merged weight pack: one launch for all four weights ----
   SEGS=1: [hi] (stride K). SEGS=2: [hi|lo] (stride 2K).                 */
__device__ __forceinline__ void pack_seg(
        const float* __restrict__ w, unsigned short* __restrict__ wp,
        int K, int segs, int i) {
    int kq = K >> 2;
    int row = i / kq;
    int c = (i - row * kq) << 2;
    float4 v = *(const float4*)(w + (size_t)row * K + c);
    short4v hi, lo;
    hi.x = f2bf(v.x); hi.y = f2bf(v.y); hi.z = f2bf(v.z); hi.w = f2bf(v.w);
    lo.x = f2bf(v.x - bf2f(hi.x)); lo.y = f2bf(v.y - bf2f(hi.y));
    lo.z = f2bf(v.z - bf2f(hi.z)); lo.w = f2bf(v.w - bf2f(hi.w));
    size_t b0 = (size_t)row * (segs * K) + c;
    *(short4v*)(wp + b0) = hi;
    if (segs == 2) *(short4v*)(wp + b0 + K) = lo;
}

__global__ __launch_bounds__(256) void wpack_all_kernel(
        const float* __restrict__ win,  unsigned short* __restrict__ pin,
        const float* __restrict__ wout, unsigned short* __restrict__ pout,
        const float* __restrict__ wx,   unsigned short* __restrict__ px,
        const float* __restrict__ wdt,  unsigned short* __restrict__ pdt) {
    int bid = blockIdx.x;
    int t = threadIdx.x;
    if (bid < 4096) {                 /* in_proj [4096][1024] -> [hi] */
        pack_seg(win, pin, HIDDEN, 1, bid * 256 + t);
    } else if (bid < 6144) {          /* out_proj [1024][2048] -> [hi|lo] */
        pack_seg(wout, pout, D_INNER, 2, (bid - 4096) * 256 + t);
    } else if (bid < 6336) {          /* x_proj [96][2048] -> [hi|lo] */
        pack_seg(wx, px, D_INNER, 2, (bid - 6144) * 256 + t);
    } else {                          /* dt_proj [2048][64] -> [hi|lo] */
        pack_seg(wdt, pdt, DT_RANK, 2, (bid - 6336) * 256 + t);
    }
}

/* ---- RMSNorm + [hi|lo] act pack: x[row,1024] -> xn_p[row,2048] ---- */
__global__ __launch_bounds__(256) void rmsnorm_pack_kernel(
        const float* __restrict__ x, const float* __restrict__ w,
        unsigned short* __restrict__ xn_p) {
    int row = blockIdx.x;
    float4 v = ((const float4*)(x + (size_t)row * HIDDEN))[threadIdx.x];
    float ss = v.x*v.x + v.y*v.y + v.z*v.z + v.w*v.w;
    #pragma unroll
    for (int off = 32; off; off >>= 1) ss += __shfl_down(ss, off);
    __shared__ float wsum[4];
    if ((threadIdx.x & 63) == 0) wsum[threadIdx.x >> 6] = ss;
    __syncthreads();
    float scale = rsqrtf((wsum[0] + wsum[1] + wsum[2] + wsum[3]) / (float)HIDDEN + 1e-5f);
    float4 wv = ((const float4*)w)[threadIdx.x];
    float o0 = v.x * scale * wv.x, o1 = v.y * scale * wv.y;
    float o2 = v.z * scale * wv.z, o3 = v.w * scale * wv.w;
    short4v hi, lo;
    hi.x = f2bf(o0); hi.y = f2bf(o1); hi.z = f2bf(o2); hi.w = f2bf(o3);
    lo.x = f2bf(o0 - bf2f(hi.x)); lo.y = f2bf(o1 - bf2f(hi.y));
    lo.z = f2bf(o2 - bf2f(hi.z)); lo.w = f2bf(o3 - bf2f(hi.w));
    size_t b0 = (size_t)row * (2 * HIDDEN) + threadIdx.x * 4;
    *(short4v*)&xn_p[b0]          = hi;
    *(short4v*)&xn_p[b0 + HIDDEN] = lo;
}

/* ---- in_proj 2-term GEMM, 128x256 tile, LDS 64KB (round-8 proven) ----
   C[4096,4096] = (Ah+Al)[4096,1024] @ Wh[4096,1024]^T
   cols < 2048 -> xi ; cols >= 2048 -> res (block-uniform split)        */
__global__ __launch_bounds__(256, 2) void mgemm_in_kernel(
        const unsigned short* __restrict__ Ap,   /* [4096][2048] hi|lo */
        const unsigned short* __restrict__ Wp,   /* [4096][1024] hi    */
        float* __restrict__ C0, float* __restrict__ C1) {
    __shared__ short Ah[128 * 64];
    __shared__ short Al[128 * 64];
    __shared__ short Bh[256 * 64];
    const int t = threadIdx.x;
    const int w = t >> 6, l = t & 63;
    const int m0 = blockIdx.y * 128, n0 = blockIdx.x * 256;
    const int lrow = l & 15;
    f32x4 acc[8][4];
    #pragma unroll
    for (int m = 0; m < 8; ++m)
        #pragma unroll
        for (int n = 0; n < 4; ++n) {
            acc[m][n].x = 0.f; acc[m][n].y = 0.f; acc[m][n].z = 0.f; acc[m][n].w = 0.f;
        }
    const int srow8 = l >> 3;                       /* 0..7 */
    const int sc8   = (l & 7) ^ srow8;              /* pre-swizzled col8 */
    const unsigned short* ga = Ap + (size_t)(m0 + w * 32 + srow8) * 2048 + sc8 * 8;
    const unsigned short* gb = Wp + (size_t)(n0 + w * 64 + srow8) * 1024 + sc8 * 8;
    for (int k0 = 0; k0 < 1024; k0 += 64) {
        __syncthreads();
        #pragma unroll
        for (int q = 0; q < 4; ++q) {
            const int ar = (w * 32 + q * 8) * 128;  /* byte offset */
            GLOAD(ga + k0 + (size_t)q * 8 * 2048,        (char*)Ah + ar);
            GLOAD(ga + 1024 + k0 + (size_t)q * 8 * 2048, (char*)Al + ar);
        }
        #pragma unroll
        for (int q = 0; q < 8; ++q)
            GLOAD(gb + k0 + (size_t)q * 8 * 1024, (char*)Bh + (w * 64 + q * 8) * 128);
        __syncthreads();
        #pragma unroll
        for (int kk = 0; kk < 2; ++kk) {
            const int slot = ((kk * 4 + (l >> 4)) ^ (l & 7)) * 8;
            bf16x8 bh[4];
            #pragma unroll
            for (int n = 0; n < 4; ++n)
                bh[n] = *(const bf16x8*)&Bh[(w * 64 + n * 16 + lrow) * 64 + slot];
            #pragma unroll
            for (int m = 0; m < 8; ++m) {
                bf16x8 ah = *(const bf16x8*)&Ah[(m * 16 + lrow) * 64 + slot];
                bf16x8 al = *(const bf16x8*)&Al[(m * 16 + lrow) * 64 + slot];
                #pragma unroll
                for (int n = 0; n < 4; ++n) {
                    acc[m][n] = __builtin_amdgcn_mfma_f32_16x16x32_bf16(
                        ah, bh[n], acc[m][n], 0, 0, 0);
                    acc[m][n] = __builtin_amdgcn_mfma_f32_16x16x32_bf16(
                        al, bh[n], acc[m][n], 0, 0, 0);
                }
            }
        }
    }
    float* dst = (n0 < D_INNER) ? C0 : C1;
    const int cbase = (n0 < D_INNER) ? n0 : n0 - D_INNER;
    #pragma unroll
    for (int m = 0; m < 8; ++m) {
        #pragma unroll
        for (int n = 0; n < 4; ++n) {
            #pragma unroll
            for (int j = 0; j < 4; ++j) {
                int row = m0 + m * 16 + (l >> 4) * 4 + j;
                int col = cbase + w * 64 + n * 16 + (l & 15);
                dst[(size_t)row * D_INNER + col] = acc[m][n][j];
            }
        }
    }
}

/* ---- component-packed split-bf16 MFMA GEMM (128x128) ----
   TERMS=3: C = Ah·Wh + Ah·Wl + Al·Wh  (A [hi|lo] stride 2K, W [hi|lo] stride 2K)
   EPI 2: partial store to C0 + z*partStride
   EPI 3: softplus(v + bias[col]) -> C0                                   */
template<int TERMS, int EPI>
__global__ __launch_bounds__(256) void mgemm_kernel(
        const unsigned short* __restrict__ Ap, const unsigned short* __restrict__ Wp,
        int Klog, int klen, int brows, float* __restrict__ C0, float* __restrict__ C1,
        int splitN, int ldout, size_t partStride, const float* __restrict__ bias) {
    constexpr int NT = (TERMS == 3) ? 4 : 3;
    __shared__ short lds[NT * 128 * 64];
    short* Ah = lds;
    short* Al = lds + 128 * 64;
    short* Bh = lds + 2 * 128 * 64;
    short* Bl = lds + 3 * 128 * 64;
    const int t = threadIdx.x;
    const int w = t >> 6, l = t & 63;
    const int m0 = blockIdx.y * 128, n0 = blockIdx.x * 128;
    const int kbeg = blockIdx.z * klen;
    const int wr = (w >> 1) * 64, wc = (w & 1) * 64;
    const int lrow = l & 15;
    f32x4 acc[4][4];
    #pragma unroll
    for (int m = 0; m < 4; ++m)
        #pragma unroll
        for (int n = 0; n < 4; ++n) {
            acc[m][n].x = 0.f; acc[m][n].y = 0.f; acc[m][n].z = 0.f; acc[m][n].w = 0.f;
        }
    const int Asr = 2 * Klog;
    const int Wsr = 2 * Klog;
    const int srow = w * 32 + (l >> 3);
    const int sc8  = (l & 7) ^ ((l >> 3) & 7);
    const int brow = min(n0 + srow, brows - 1);   /* clamp for padded-N */
    const unsigned short* ga = Ap + (size_t)(m0 + srow) * Asr + sc8 * 8;
    const unsigned short* gb = Wp + (size_t)brow * Wsr + sc8 * 8;
    for (int k0 = kbeg; k0 < kbeg + klen; k0 += 64) {
        __syncthreads();
        #pragma unroll
        for (int q = 0; q < 4; ++q) {
            const int doff = (w * 32 + q * 8) * 128;
            GLOAD(ga + k0 + (size_t)q * 8 * Asr,        (char*)Ah + doff);
            GLOAD(ga + Klog + k0 + (size_t)q * 8 * Asr, (char*)Al + doff);
            GLOAD(gb + k0 + (size_t)q * 8 * Wsr,        (char*)Bh + doff);
            GLOAD(gb + Klog + k0 + (size_t)q * 8 * Wsr, (char*)Bl + doff);
        }
        __syncthreads();
        #pragma unroll
        for (int kk = 0; kk < 2; ++kk) {
            const int slot = ((kk * 4 + (l >> 4)) ^ (l & 7)) * 8;
            bf16x8 ah[4], al[4], bh[4], bl[4];
            #pragma unroll
            for (int m = 0; m < 4; ++m) {
                ah[m] = *(const bf16x8*)&Ah[(wr + m * 16 + lrow) * 64 + slot];
                al[m] = *(const bf16x8*)&Al[(wr + m * 16 + lrow) * 64 + slot];
            }
            #pragma unroll
            for (int n = 0; n < 4; ++n) {
                bh[n] = *(const bf16x8*)&Bh[(wc + n * 16 + lrow) * 64 + slot];
                bl[n] = *(const bf16x8*)&Bl[(wc + n * 16 + lrow) * 64 + slot];
            }
            #pragma unroll
            for (int m = 0; m < 4; ++m)
                #pragma unroll
                for (int n = 0; n < 4; ++n) {
                    acc[m][n] = __builtin_amdgcn_mfma_f32_16x16x32_bf16(
                        ah[m], bh[n], acc[m][n], 0, 0, 0);
                    acc[m][n] = __builtin_amdgcn_mfma_f32_16x16x32_bf16(
                        al[m], bh[n], acc[m][n], 0, 0, 0);
                    acc[m][n] = __builtin_amdgcn_mfma_f32_16x16x32_bf16(
                        ah[m], bl[n], acc[m][n], 0, 0, 0);
                }
        }
    }
    float* dst = (EPI == 2) ? (C0 + blockIdx.z * partStride) : C0;
    #pragma unroll
    for (int m = 0; m < 4; ++m) {
        #pragma unroll
        for (int n = 0; n < 4; ++n) {
            #pragma unroll
            for (int j = 0; j < 4; ++j) {
                int row = m0 + wr + m * 16 + (l >> 4) * 4 + j;
                int col = n0 + wc + n * 16 + (l & 15);
                float v = acc[m][n][j];
                if (EPI == 2) {
                    dst[(size_t)row * ldout + col] = v;
                } else {
                    C0[(size_t)row * ldout + col] = softplus_f(v + bias[col]);
                }
            }
        }
    }
}

/* ---- reduce 2 split-K partials + residual x -> out (out_proj) ---- */
__global__ __launch_bounds__(256) void reduce2_kernel(
        const float* __restrict__ parts, size_t partStride,
        const float* __restrict__ x, float* __restrict__ out) {
    size_t i = (size_t)blockIdx.x * 256 + threadIdx.x;   /* float4 index */
    float4 a = ((const float4*)(parts))[i];
    float4 b = ((const float4*)(parts + partStride))[i];
    float4 xv = ((const float4*)x)[i];
    float4 o;
    o.x = a.x + b.x + xv.x;
    o.y = a.y + b.y + xv.y;
    o.z = a.z + b.z + xv.z;
    o.w = a.w + b.w + xv.w;
    ((float4*)out)[i] = o;
}

/* ---- reduce 8 x_proj partials -> xdbl fp32 [4096,96] + dtp_p [hi|lo] [4096,128] ---- */
__global__ __launch_bounds__(256) void reduceX_kernel(
        const float* __restrict__ parts, float* __restrict__ xdbl,
        unsigned short* __restrict__ dtp) {
    int i = blockIdx.x * 256 + threadIdx.x;      /* 4096*24 total */
    int row = i / 24;
    int c = (i - row * 24) * 4;
    float4 s = make_float4(0.f, 0.f, 0.f, 0.f);
    #pragma unroll
    for (int z = 0; z < 8; ++z) {
        float4 a = *(const float4*)(parts + (size_t)z * 524288 + (size_t)row * 128 + c);
        s.x += a.x; s.y += a.y; s.z += a.z; s.w += a.w;
    }
    *(float4*)(xdbl + (size_t)row * XDBL + c) = s;
    if (c < DT_RANK) {
        short4v hi, lo;
        hi.x = f2bf(s.x); hi.y = f2bf(s.y); hi.z = f2bf(s.z); hi.w = f2bf(s.w);
        lo.x = f2bf(s.x - bf2f(hi.x)); lo.y = f2bf(s.y - bf2f(hi.y));
        lo.z = f2bf(s.z - bf2f(hi.z)); lo.w = f2bf(s.w - bf2f(hi.w));
        size_t b0 = (size_t)row * 128 + c;
        *(short4v*)(dtp + b0)      = hi;
        *(short4v*)(dtp + b0 + 64) = lo;
    }
}

/* ---- causal depthwise conv (d_conv=4) + SiLU -> [hi|lo] packed xc ---- */
__global__ __launch_bounds__(256) void conv_silu_kernel(
        const float* __restrict__ xi, const float* __restrict__ w,
        const float* __restrict__ b, unsigned short* __restrict__ xc_p) {
    size_t i = (size_t)blockIdx.x * 256 + threadIdx.x;
    int d = (int)(i & (D_INNER - 1));
    int tt = (int)(i >> 11);
    int s = tt & (SEQ - 1);
    float4 wv = ((const float4*)w)[d];
    float acc = b[d];
    if (s >= 3) acc += wv.x * xi[i - 3 * D_INNER];
    if (s >= 2) acc += wv.y * xi[i - 2 * D_INNER];
    if (s >= 1) acc += wv.z * xi[i - 1 * D_INNER];
    acc += wv.w * xi[i];
    float o = silu_f(acc);
    unsigned short hi = f2bf(o);
    unsigned short lo = f2bf(o - bf2f(hi));
    size_t o2 = (size_t)tt * (2 * D_INNER) + d;
    xc_p[o2]           = hi;
    xc_p[o2 + D_INNER] = lo;
}

/* ==== selective scan: thread-per-(b,d,chunk), states in registers.
   B/C rows staged in LDS once per chunk (uniform-read broadcast).   ==== */

__global__ __launch_bounds__(256) void scanA_kernel(
        const unsigned short* __restrict__ xcp, const float* __restrict__ delta,
        const float* __restrict__ xdbl, const float* __restrict__ A_log,
        float* __restrict__ hpart, float* __restrict__ Pp) {
    __shared__ float sB[CHL * NSTATE];
    const int bid = blockIdx.x;            /* 1024 blocks */
    const int b    = bid >> 9;
    const int c    = (bid >> 3) & 63;
    const int dblk = bid & 7;
    const int d    = (dblk << 8) + threadIdx.x;
    const int rowbase = b * SEQ + c * CHL;
    /* stage B rows for the whole chunk: 512 floats */
    #pragma unroll
    for (int q = 0; q < 2; ++q) {
        int e = threadIdx.x + q * 256;
        int r = e >> 4, n = e & 15;
        sB[e] = xdbl[(size_t)(rowbase + r) * XDBL + DT_RANK + n];
    }
    float adn[NSTATE];
    #pragma unroll
    for (int k = 0; k < 4; ++k) {
        float4 a = *(const float4*)(A_log + d * NSTATE + k * 4);
        adn[k*4+0] = -__expf(a.x); adn[k*4+1] = -__expf(a.y);
        adn[k*4+2] = -__expf(a.z); adn[k*4+3] = -__expf(a.w);
    }
    float h[NSTATE], P[NSTATE];
    #pragma unroll
    for (int n = 0; n < NSTATE; ++n) { h[n] = 0.f; P[n] = 1.f; }
    __syncthreads();
    #pragma unroll 4
    for (int r = 0; r < CHL; ++r) {
        const int row = rowbase + r;
        const float* brow = &sB[r * NSTATE];
        size_t o2 = (size_t)row * (2 * D_INNER) + d;
        float dl = delta[(size_t)row * D_INNER + d];
        float u  = bf2f(xcp[o2]) + bf2f(xcp[o2 + D_INNER]);
        float du = dl * u;
        #pragma unroll
        for (int n = 0; n < NSTATE; ++n) {
            float dA = __expf(dl * adn[n]);
            h[n] = fmaf(dA, h[n], du * brow[n]);
            P[n] *= dA;
        }
    }
    size_t base = (size_t)c * BDN + (size_t)(b * D_INNER + d) * NSTATE;
    #pragma unroll
    for (int k = 0; k < 4; ++k) {
        *(float4*)(hpart + base + k * 4) = make_float4(h[k*4], h[k*4+1], h[k*4+2], h[k*4+3]);
        *(float4*)(Pp    + base + k * 4) = make_float4(P[k*4], P[k*4+1], P[k*4+2], P[k*4+3]);
    }
}

/* scanB: hstart written IN PLACE over hpart (read hp/P before writing). */
__global__ __launch_bounds__(256) void scanB_kernel(
        float* __restrict__ hpart, const float* __restrict__ Pp) {
    int idx = blockIdx.x * 256 + threadIdx.x;
    float h = 0.f;
    for (int c = 0; c < NCH; ++c) {
        size_t o = (size_t)c * BDN + idx;
        float hp = hpart[o];
        float p  = Pp[o];
        hpart[o] = h;                 /* hstart for chunk c */
        h = fmaf(p, h, hp);
    }
}

/* scanC: y_p aliases xcp (in-place, per-cell exclusive ownership). */
__global__ __launch_bounds__(256) void scanC_kernel(
        const unsigned short* xcp, const float* __restrict__ delta,
        const float* __restrict__ xdbl, const float* __restrict__ A_log,
        const float* __restrict__ Dp, const float* __restrict__ hstart,
        const float* __restrict__ res, unsigned short* y_p) {
    __shared__ float sB[CHL * NSTATE];
    __shared__ float sC[CHL * NSTATE];
    const int bid = blockIdx.x;            /* 1024 blocks */
    const int b    = bid >> 9;
    const int c    = (bid >> 3) & 63;
    const int dblk = bid & 7;
    const int d    = (dblk << 8) + threadIdx.x;
    const int rowbase = b * SEQ + c * CHL;
    #pragma unroll
    for (int q = 0; q < 2; ++q) {
        int e = threadIdx.x + q * 256;
        int r = e >> 4, n = e & 15;
        sB[e] = xdbl[(size_t)(rowbase + r) * XDBL + DT_RANK + n];
        sC[e] = xdbl[(size_t)(rowbase + r) * XDBL + DT_RANK + NSTATE + n];
    }
    float adn[NSTATE];
    #pragma unroll
    for (int k = 0; k < 4; ++k) {
        float4 a = *(const float4*)(A_log + d * NSTATE + k * 4);
        adn[k*4+0] = -__expf(a.x); adn[k*4+1] = -__expf(a.y);
        adn[k*4+2] = -__expf(a.z); adn[k*4+3] = -__expf(a.w);
    }
    const float Dd = Dp[d];
    float h[NSTATE];
    size_t base = (size_t)c * BDN + (size_t)(b * D_INNER + d) * NSTATE;
    #pragma unroll
    for (int k = 0; k < 4; ++k) {
        float4 hv = *(const float4*)(hstart + base + k * 4);
        h[k*4] = hv.x; h[k*4+1] = hv.y; h[k*4+2] = hv.z; h[k*4+3] = hv.w;
    }
    __syncthreads();
    #pragma unroll 4
    for (int r = 0; r < CHL; ++r) {
        const int row = rowbase + r;
        const float* brow = &sB[r * NSTATE];
        const float* crow = &sC[r * NSTATE];
        size_t o2 = (size_t)row * (2 * D_INNER) + d;
        float dl = delta[(size_t)row * D_INNER + d];
        float u  = bf2f(xcp[o2]) + bf2f(xcp[o2 + D_INNER]);
        float du = dl * u;
        float ys[4];
        ys[0] = u * Dd; ys[1] = 0.f; ys[2] = 0.f; ys[3] = 0.f;
        #pragma unroll
        for (int n = 0; n < NSTATE; ++n) {
            float dA = __expf(dl * adn[n]);
            h[n] = fmaf(dA, h[n], du * brow[n]);
            ys[n & 3] = fmaf(h[n], crow[n], ys[n & 3]);
        }
        float ysum = (ys[0] + ys[1]) + (ys[2] + ys[3]);
        float rv = res[(size_t)row * D_INNER + d];
        float gv = ysum * silu_f(rv);
        unsigned short hi = f2bf(gv);
        unsigned short lo = f2bf(gv - bf2f(hi));
        y_p[o2]           = hi;
        y_p[o2 + D_INNER] = lo;
    }
}

extern "C" void kernel_launch(void* const* d_in, const int* in_sizes, int n_in,
                              void* d_out, int out_size, void* d_ws, size_t ws_size,
                              hipStream_t stream) {
    const float* x         = (const float*)d_in[0];
    const float* norm_w    = (const float*)d_in[1];
    const float* in_proj_w = (const float*)d_in[2];
    const float* conv_w    = (const float*)d_in[3];
    const float* conv_b    = (const float*)d_in[4];
    const float* x_proj_w  = (const float*)d_in[5];
    const float* dt_proj_w = (const float*)d_in[6];
    const float* dt_proj_b = (const float*)d_in[7];
    const float* A_log     = (const float*)d_in[8];
    const float* Dp        = (const float*)d_in[9];
    const float* out_proj_w= (const float*)d_in[10];
    float* out = (float*)d_out;
    float* ws  = (float*)d_ws;

    const size_t M8 = (size_t)T_TOK * D_INNER;           /* 8388608 */
    float* res   = ws;                                    /* 8M fl; dead after scanC */
    float* delta = res + M8;                              /* 8M fl; dead after scanC */
    float* xdbl  = delta + M8;                            /* 393216 fl */
    unsigned short* xn_p   = (unsigned short*)(xdbl + (size_t)T_TOK * XDBL);
    unsigned short* w_in_p = xn_p   + (size_t)4096 * 2048;   /* 4096x1024 sh */
    unsigned short* w_out_p= w_in_p + (size_t)4096 * 1024;   /* 1024x4096 sh */
    unsigned short* w_xp_p = w_out_p+ (size_t)1024 * 4096;   /* 96x4096 sh */
    unsigned short* w_dt_p = w_xp_p + (size_t)96 * 4096;     /* 2048x128 sh */
    unsigned short* xc_p   = w_dt_p + (size_t)2048 * 128;    /* 4096x4096 sh */
    unsigned short* dtp_p  = xc_p   + (size_t)4096 * 4096;   /* 4096x128 sh */
    float* xi    = (float*)(dtp_p + (size_t)4096 * 128);     /* 8M fl */
    float* hpart = xi;                          /* xi dead after conv; hstart in-place */
    float* Pp    = xi + (size_t)BDN * NCH;
    float* parts_x = delta;                     /* 8x524288 fl, pre-dt_proj */
    unsigned short* y_p = xc_p;                 /* in-place over packed xc */
    float* parts = ws;                          /* res+delta region (dead after scanC) */
    const size_t partStride = (size_t)T_TOK * HIDDEN;        /* 4194304 */

    /* merged weight packs: [hi], [hi|lo], [hi|lo], [hi|lo] */
    wpack_all_kernel<<<6464, 256, 0, stream>>>(in_proj_w, w_in_p, out_proj_w, w_out_p,
                                               x_proj_w, w_xp_p, dt_proj_w, w_dt_p);

    /* RMSNorm + [hi|lo] pack */
    rmsnorm_pack_kernel<<<T_TOK, 256, 0, stream>>>(x, norm_w, xn_p);

    { /* in_proj (2-term, 128x256 tile): -> xi | res */
        dim3 g(4096 / 256, T_TOK / 128, 1);
        mgemm_in_kernel<<<g, 256, 0, stream>>>(xn_p, w_in_p, xi, res);
    }

    /* conv + SiLU -> [hi|lo] packed xc */
    conv_silu_kernel<<<(int)(M8 / 256), 256, 0, stream>>>(xi, conv_w, conv_b, xc_p);

    { /* x_proj (3-term, split-K=8, N padded 96->128): partials */
        dim3 g(1, T_TOK / 128, 8);
        mgemm_kernel<3, 2><<<g, 256, 0, stream>>>(xc_p, w_xp_p, D_INNER, D_INNER / 8,
                                                  96, parts_x, nullptr, 0, 128, 524288, nullptr);
    }
    reduceX_kernel<<<T_TOK * 24 / 256, 256, 0, stream>>>(parts_x, xdbl, dtp_p);

    { /* dt_proj (3-term) + bias + softplus -> delta */
        dim3 g(D_INNER / 128, T_TOK / 128, 1);
        mgemm_kernel<3, 3><<<g, 256, 0, stream>>>(dtp_p, w_dt_p, DT_RANK, DT_RANK,
                                                  D_INNER, delta, nullptr, 0, D_INNER, 0, dt_proj_b);
    }

    /* selective scan */
    scanA_kernel<<<BATCH * NCH * 8, 256, 0, stream>>>(xc_p, delta, xdbl, A_log, hpart, Pp);
    scanB_kernel<<<BDN / 256, 256, 0, stream>>>(hpart, Pp);
    scanC_kernel<<<BATCH * NCH * 8, 256, 0, stream>>>(xc_p, delta, xdbl, A_log, Dp,
                                                      hpart, res, y_p);

    { /* out_proj (3-term, split-K=2): partials */
        dim3 g(HIDDEN / 128, T_TOK / 128, 2);
        mgemm_kernel<3, 2><<<g, 256, 0, stream>>>(y_p, w_out_p, D_INNER, D_INNER / 2,
                                                  HIDDEN, parts, nullptr, 0, HIDDEN, partStride, nullptr);
    }
    /* residual + reduce */
    reduce2_kernel<<<(int)(partStride / 4 / 256), 256, 0, stream>>>(parts, partStride, x, out);
}

// Round 11
// 295.611 us; speedup vs baseline: 1.0777x; 1.0278x over previous
//
#include <hip/hip_runtime.h>
#include <math.h>

#define HIDDEN   1024
#define D_INNER  2048
#define NSTATE   16
#define DT_RANK  64
#define BATCH    2
#define SEQ      2048
#define T_TOK    (BATCH * SEQ)            /* 4096 tokens */
#define XDBL     (DT_RANK + 2 * NSTATE)   /* 96 */
#define NCH      64                       /* scan chunks */
#define CHL      (SEQ / NCH)              /* 32 steps per chunk */
#define BDN      (BATCH * D_INNER * NSTATE) /* 65536 */

typedef float f32x4   __attribute__((ext_vector_type(4)));
typedef short bf16x8  __attribute__((ext_vector_type(8)));
typedef short short4v __attribute__((ext_vector_type(4)));

#define AS1 __attribute__((address_space(1)))
#define AS3 __attribute__((address_space(3)))
#define GLOAD(src, dst) __builtin_amdgcn_global_load_lds( \
    (const AS1 unsigned int*)(src), (AS3 unsigned int*)(dst), 16, 0, 0)

__device__ __forceinline__ float silu_f(float x) { return x / (1.0f + __expf(-x)); }
__device__ __forceinline__ float softplus_f(float x) {
    return fmaxf(x, 0.0f) + log1pf(__expf(-fabsf(x)));
}
__device__ __forceinline__ unsigned short f2bf(float x) {
    unsigned int u = __float_as_uint(x);
    u += 0x7fffu + ((u >> 16) & 1u);           /* RNE */
    return (unsigned short)(u >> 16);
}
__device__ __forceinline__ float bf2f(unsigned short h) {
    return __uint_as_float(((unsigned int)h) << 16);
}

/* ---- merged weight pack: one launch for all four weights ----
   segs=1: [hi] (stride K). segs=2: [hi|lo] (stride 2K).                 */
__device__ __forceinline__ void pack_seg(
        const float* __restrict__ w, unsigned short* __restrict__ wp,
        int K, int segs, int i) {
    int kq = K >> 2;
    int row = i / kq;
    int c = (i - row * kq) << 2;
    float4 v = *(const float4*)(w + (size_t)row * K + c);
    short4v hi, lo;
    hi.x = f2bf(v.x); hi.y = f2bf(v.y); hi.z = f2bf(v.z); hi.w = f2bf(v.w);
    lo.x = f2bf(v.x - bf2f(hi.x)); lo.y = f2bf(v.y - bf2f(hi.y));
    lo.z = f2bf(v.z - bf2f(hi.z)); lo.w = f2bf(v.w - bf2f(hi.w));
    size_t b0 = (size_t)row * (segs * K) + c;
    *(short4v*)(wp + b0) = hi;
    if (segs == 2) *(short4v*)(wp + b0 + K) = lo;
}

__global__ __launch_bounds__(256) void wpack_all_kernel(
        const float* __restrict__ win,  unsigned short* __restrict__ pin,
        const float* __restrict__ wout, unsigned short* __restrict__ pout,
        const float* __restrict__ wx,   unsigned short* __restrict__ px,
        const float* __restrict__ wdt,  unsigned short* __restrict__ pdt) {
    int bid = blockIdx.x;
    int t = threadIdx.x;
    if (bid < 4096) {                 /* in_proj [4096][1024] -> [hi] */
        pack_seg(win, pin, HIDDEN, 1, bid * 256 + t);
    } else if (bid < 6144) {          /* out_proj [1024][2048] -> [hi] */
        pack_seg(wout, pout, D_INNER, 1, (bid - 4096) * 256 + t);
    } else if (bid < 6336) {          /* x_proj [96][2048] -> [hi|lo] */
        pack_seg(wx, px, D_INNER, 2, (bid - 6144) * 256 + t);
    } else {                          /* dt_proj [2048][64] -> [hi|lo] */
        pack_seg(wdt, pdt, DT_RANK, 2, (bid - 6336) * 256 + t);
    }
}

/* ---- RMSNorm + [hi|lo] act pack: x[row,1024] -> xn_p[row,2048] ---- */
__global__ __launch_bounds__(256) void rmsnorm_pack_kernel(
        const float* __restrict__ x, const float* __restrict__ w,
        unsigned short* __restrict__ xn_p) {
    int row = blockIdx.x;
    float4 v = ((const float4*)(x + (size_t)row * HIDDEN))[threadIdx.x];
    float ss = v.x*v.x + v.y*v.y + v.z*v.z + v.w*v.w;
    #pragma unroll
    for (int off = 32; off; off >>= 1) ss += __shfl_down(ss, off);
    __shared__ float wsum[4];
    if ((threadIdx.x & 63) == 0) wsum[threadIdx.x >> 6] = ss;
    __syncthreads();
    float scale = rsqrtf((wsum[0] + wsum[1] + wsum[2] + wsum[3]) / (float)HIDDEN + 1e-5f);
    float4 wv = ((const float4*)w)[threadIdx.x];
    float o0 = v.x * scale * wv.x, o1 = v.y * scale * wv.y;
    float o2 = v.z * scale * wv.z, o3 = v.w * scale * wv.w;
    short4v hi, lo;
    hi.x = f2bf(o0); hi.y = f2bf(o1); hi.z = f2bf(o2); hi.w = f2bf(o3);
    lo.x = f2bf(o0 - bf2f(hi.x)); lo.y = f2bf(o1 - bf2f(hi.y));
    lo.z = f2bf(o2 - bf2f(hi.z)); lo.w = f2bf(o3 - bf2f(hi.w));
    size_t b0 = (size_t)row * (2 * HIDDEN) + threadIdx.x * 4;
    *(short4v*)&xn_p[b0]          = hi;
    *(short4v*)&xn_p[b0 + HIDDEN] = lo;
}

/* ---- 2-term GEMM, 128x256 tile, LDS 64KB, 2 blocks/CU ----
   C[M,N] = (Ah+Al)[M,Klog] @ Wh[N,Klog]^T  over k in [z*klen,(z+1)*klen)
   A row stride Asr with lo at +loOff; W row stride Wsr ([hi] only).
   EPI 0: block cols < D_INNER -> C0 else C1 (in_proj)
   EPI 2: partial store to C0 + z*partStride (out_proj split-K)         */
template<int EPI>
__global__ __launch_bounds__(256, 2) void mgemm2_kernel(
        const unsigned short* __restrict__ Ap, int Asr, int loOff,
        const unsigned short* __restrict__ Wp, int Wsr,
        int klen, float* __restrict__ C0, float* __restrict__ C1,
        int ldout, size_t partStride) {
    __shared__ short Ah[128 * 64];
    __shared__ short Al[128 * 64];
    __shared__ short Bh[256 * 64];
    const int t = threadIdx.x;
    const int w = t >> 6, l = t & 63;
    const int m0 = blockIdx.y * 128, n0 = blockIdx.x * 256;
    const int kbeg = blockIdx.z * klen;
    const int lrow = l & 15;
    f32x4 acc[8][4];
    #pragma unroll
    for (int m = 0; m < 8; ++m)
        #pragma unroll
        for (int n = 0; n < 4; ++n) {
            acc[m][n].x = 0.f; acc[m][n].y = 0.f; acc[m][n].z = 0.f; acc[m][n].w = 0.f;
        }
    const int srow8 = l >> 3;                       /* 0..7 */
    const int sc8   = (l & 7) ^ srow8;              /* pre-swizzled col8 */
    const unsigned short* ga = Ap + (size_t)(m0 + w * 32 + srow8) * Asr + sc8 * 8;
    const unsigned short* gb = Wp + (size_t)(n0 + w * 64 + srow8) * Wsr + sc8 * 8;
    for (int k0 = kbeg; k0 < kbeg + klen; k0 += 64) {
        __syncthreads();
        #pragma unroll
        for (int q = 0; q < 4; ++q) {
            const int ar = (w * 32 + q * 8) * 128;  /* byte offset */
            GLOAD(ga + k0 + (size_t)q * 8 * Asr,         (char*)Ah + ar);
            GLOAD(ga + loOff + k0 + (size_t)q * 8 * Asr, (char*)Al + ar);
        }
        #pragma unroll
        for (int q = 0; q < 8; ++q)
            GLOAD(gb + k0 + (size_t)q * 8 * Wsr, (char*)Bh + (w * 64 + q * 8) * 128);
        __syncthreads();
        #pragma unroll
        for (int kk = 0; kk < 2; ++kk) {
            const int slot = ((kk * 4 + (l >> 4)) ^ (l & 7)) * 8;
            bf16x8 bh[4];
            #pragma unroll
            for (int n = 0; n < 4; ++n)
                bh[n] = *(const bf16x8*)&Bh[(w * 64 + n * 16 + lrow) * 64 + slot];
            #pragma unroll
            for (int m = 0; m < 8; ++m) {
                bf16x8 ah = *(const bf16x8*)&Ah[(m * 16 + lrow) * 64 + slot];
                bf16x8 al = *(const bf16x8*)&Al[(m * 16 + lrow) * 64 + slot];
                #pragma unroll
                for (int n = 0; n < 4; ++n) {
                    acc[m][n] = __builtin_amdgcn_mfma_f32_16x16x32_bf16(
                        ah, bh[n], acc[m][n], 0, 0, 0);
                    acc[m][n] = __builtin_amdgcn_mfma_f32_16x16x32_bf16(
                        al, bh[n], acc[m][n], 0, 0, 0);
                }
            }
        }
    }
    float* dst;
    int cbase;
    if (EPI == 0) {
        dst   = (n0 < D_INNER) ? C0 : C1;
        cbase = (n0 < D_INNER) ? n0 : n0 - D_INNER;
    } else {
        dst   = C0 + blockIdx.z * partStride;
        cbase = n0;
    }
    #pragma unroll
    for (int m = 0; m < 8; ++m) {
        #pragma unroll
        for (int n = 0; n < 4; ++n) {
            #pragma unroll
            for (int j = 0; j < 4; ++j) {
                int row = m0 + m * 16 + (l >> 4) * 4 + j;
                int col = cbase + w * 64 + n * 16 + (l & 15);
                dst[(size_t)row * ldout + col] = acc[m][n][j];
            }
        }
    }
}

/* ---- component-packed 3-term split-bf16 GEMM (128x128) — x_proj / dt_proj ----
   C = Ah·Wh + Ah·Wl + Al·Wh  (A [hi|lo] stride 2K, W [hi|lo] stride 2K)
   EPI 2: partial store to C0 + z*partStride
   EPI 3: softplus(v + bias[col]) -> C0                                   */
template<int EPI>
__global__ __launch_bounds__(256) void mgemm_kernel(
        const unsigned short* __restrict__ Ap, const unsigned short* __restrict__ Wp,
        int Klog, int klen, int brows, float* __restrict__ C0,
        int ldout, size_t partStride, const float* __restrict__ bias) {
    __shared__ short lds[4 * 128 * 64];
    short* Ah = lds;
    short* Al = lds + 128 * 64;
    short* Bh = lds + 2 * 128 * 64;
    short* Bl = lds + 3 * 128 * 64;
    const int t = threadIdx.x;
    const int w = t >> 6, l = t & 63;
    const int m0 = blockIdx.y * 128, n0 = blockIdx.x * 128;
    const int kbeg = blockIdx.z * klen;
    const int wr = (w >> 1) * 64, wc = (w & 1) * 64;
    const int lrow = l & 15;
    f32x4 acc[4][4];
    #pragma unroll
    for (int m = 0; m < 4; ++m)
        #pragma unroll
        for (int n = 0; n < 4; ++n) {
            acc[m][n].x = 0.f; acc[m][n].y = 0.f; acc[m][n].z = 0.f; acc[m][n].w = 0.f;
        }
    const int Asr = 2 * Klog;
    const int Wsr = 2 * Klog;
    const int srow = w * 32 + (l >> 3);
    const int sc8  = (l & 7) ^ ((l >> 3) & 7);
    const int brow = min(n0 + srow, brows - 1);   /* clamp for padded-N */
    const unsigned short* ga = Ap + (size_t)(m0 + srow) * Asr + sc8 * 8;
    const unsigned short* gb = Wp + (size_t)brow * Wsr + sc8 * 8;
    for (int k0 = kbeg; k0 < kbeg + klen; k0 += 64) {
        __syncthreads();
        #pragma unroll
        for (int q = 0; q < 4; ++q) {
            const int doff = (w * 32 + q * 8) * 128;
            GLOAD(ga + k0 + (size_t)q * 8 * Asr,        (char*)Ah + doff);
            GLOAD(ga + Klog + k0 + (size_t)q * 8 * Asr, (char*)Al + doff);
            GLOAD(gb + k0 + (size_t)q * 8 * Wsr,        (char*)Bh + doff);
            GLOAD(gb + Klog + k0 + (size_t)q * 8 * Wsr, (char*)Bl + doff);
        }
        __syncthreads();
        #pragma unroll
        for (int kk = 0; kk < 2; ++kk) {
            const int slot = ((kk * 4 + (l >> 4)) ^ (l & 7)) * 8;
            bf16x8 ah[4], al[4], bh[4], bl[4];
            #pragma unroll
            for (int m = 0; m < 4; ++m) {
                ah[m] = *(const bf16x8*)&Ah[(wr + m * 16 + lrow) * 64 + slot];
                al[m] = *(const bf16x8*)&Al[(wr + m * 16 + lrow) * 64 + slot];
            }
            #pragma unroll
            for (int n = 0; n < 4; ++n) {
                bh[n] = *(const bf16x8*)&Bh[(wc + n * 16 + lrow) * 64 + slot];
                bl[n] = *(const bf16x8*)&Bl[(wc + n * 16 + lrow) * 64 + slot];
            }
            #pragma unroll
            for (int m = 0; m < 4; ++m)
                #pragma unroll
                for (int n = 0; n < 4; ++n) {
                    acc[m][n] = __builtin_amdgcn_mfma_f32_16x16x32_bf16(
                        ah[m], bh[n], acc[m][n], 0, 0, 0);
                    acc[m][n] = __builtin_amdgcn_mfma_f32_16x16x32_bf16(
                        al[m], bh[n], acc[m][n], 0, 0, 0);
                    acc[m][n] = __builtin_amdgcn_mfma_f32_16x16x32_bf16(
                        ah[m], bl[n], acc[m][n], 0, 0, 0);
                }
        }
    }
    float* dst = (EPI == 2) ? (C0 + blockIdx.z * partStride) : C0;
    #pragma unroll
    for (int m = 0; m < 4; ++m) {
        #pragma unroll
        for (int n = 0; n < 4; ++n) {
            #pragma unroll
            for (int j = 0; j < 4; ++j) {
                int row = m0 + wr + m * 16 + (l >> 4) * 4 + j;
                int col = n0 + wc + n * 16 + (l & 15);
                float v = acc[m][n][j];
                if (EPI == 2) {
                    dst[(size_t)row * ldout + col] = v;
                } else {
                    C0[(size_t)row * ldout + col] = softplus_f(v + bias[col]);
                }
            }
        }
    }
}

/* ---- reduce 4 split-K partials + residual x -> out (out_proj) ---- */
__global__ __launch_bounds__(256) void reduce4_kernel(
        const float* __restrict__ parts, size_t partStride,
        const float* __restrict__ x, float* __restrict__ out) {
    size_t i = (size_t)blockIdx.x * 256 + threadIdx.x;   /* float4 index */
    float4 a = ((const float4*)(parts))[i];
    float4 b = ((const float4*)(parts + partStride))[i];
    float4 c = ((const float4*)(parts + 2 * partStride))[i];
    float4 d = ((const float4*)(parts + 3 * partStride))[i];
    float4 xv = ((const float4*)x)[i];
    float4 o;
    o.x = a.x + b.x + c.x + d.x + xv.x;
    o.y = a.y + b.y + c.y + d.y + xv.y;
    o.z = a.z + b.z + c.z + d.z + xv.z;
    o.w = a.w + b.w + c.w + d.w + xv.w;
    ((float4*)out)[i] = o;
}

/* ---- reduce 8 x_proj partials -> xdbl fp32 [4096,96] + dtp_p [hi|lo] [4096,128] ---- */
__global__ __launch_bounds__(256) void reduceX_kernel(
        const float* __restrict__ parts, float* __restrict__ xdbl,
        unsigned short* __restrict__ dtp) {
    int i = blockIdx.x * 256 + threadIdx.x;      /* 4096*24 total */
    int row = i / 24;
    int c = (i - row * 24) * 4;
    float4 s = make_float4(0.f, 0.f, 0.f, 0.f);
    #pragma unroll
    for (int z = 0; z < 8; ++z) {
        float4 a = *(const float4*)(parts + (size_t)z * 524288 + (size_t)row * 128 + c);
        s.x += a.x; s.y += a.y; s.z += a.z; s.w += a.w;
    }
    *(float4*)(xdbl + (size_t)row * XDBL + c) = s;
    if (c < DT_RANK) {
        short4v hi, lo;
        hi.x = f2bf(s.x); hi.y = f2bf(s.y); hi.z = f2bf(s.z); hi.w = f2bf(s.w);
        lo.x = f2bf(s.x - bf2f(hi.x)); lo.y = f2bf(s.y - bf2f(hi.y));
        lo.z = f2bf(s.z - bf2f(hi.z)); lo.w = f2bf(s.w - bf2f(hi.w));
        size_t b0 = (size_t)row * 128 + c;
        *(short4v*)(dtp + b0)      = hi;
        *(short4v*)(dtp + b0 + 64) = lo;
    }
}

/* ---- causal depthwise conv (d_conv=4) + SiLU -> [hi|lo] packed xc ---- */
__global__ __launch_bounds__(256) void conv_silu_kernel(
        const float* __restrict__ xi, const float* __restrict__ w,
        const float* __restrict__ b, unsigned short* __restrict__ xc_p) {
    size_t i = (size_t)blockIdx.x * 256 + threadIdx.x;
    int d = (int)(i & (D_INNER - 1));
    int tt = (int)(i >> 11);
    int s = tt & (SEQ - 1);
    float4 wv = ((const float4*)w)[d];
    float acc = b[d];
    if (s >= 3) acc += wv.x * xi[i - 3 * D_INNER];
    if (s >= 2) acc += wv.y * xi[i - 2 * D_INNER];
    if (s >= 1) acc += wv.z * xi[i - 1 * D_INNER];
    acc += wv.w * xi[i];
    float o = silu_f(acc);
    unsigned short hi = f2bf(o);
    unsigned short lo = f2bf(o - bf2f(hi));
    size_t o2 = (size_t)tt * (2 * D_INNER) + d;
    xc_p[o2]           = hi;
    xc_p[o2 + D_INNER] = lo;
}

/* ==== selective scan: thread-per-(b,d,chunk), states in registers.
   B/C rows staged in LDS once per chunk (uniform-read broadcast).   ==== */

__global__ __launch_bounds__(256) void scanA_kernel(
        const unsigned short* __restrict__ xcp, const float* __restrict__ delta,
        const float* __restrict__ xdbl, const float* __restrict__ A_log,
        float* __restrict__ hpart, float* __restrict__ Pp) {
    __shared__ float sB[CHL * NSTATE];
    const int bid = blockIdx.x;            /* 1024 blocks */
    const int b    = bid >> 9;
    const int c    = (bid >> 3) & 63;
    const int dblk = bid & 7;
    const int d    = (dblk << 8) + threadIdx.x;
    const int rowbase = b * SEQ + c * CHL;
    #pragma unroll
    for (int q = 0; q < 2; ++q) {
        int e = threadIdx.x + q * 256;
        int r = e >> 4, n = e & 15;
        sB[e] = xdbl[(size_t)(rowbase + r) * XDBL + DT_RANK + n];
    }
    float adn[NSTATE];
    #pragma unroll
    for (int k = 0; k < 4; ++k) {
        float4 a = *(const float4*)(A_log + d * NSTATE + k * 4);
        adn[k*4+0] = -__expf(a.x); adn[k*4+1] = -__expf(a.y);
        adn[k*4+2] = -__expf(a.z); adn[k*4+3] = -__expf(a.w);
    }
    float h[NSTATE], P[NSTATE];
    #pragma unroll
    for (int n = 0; n < NSTATE; ++n) { h[n] = 0.f; P[n] = 1.f; }
    __syncthreads();
    #pragma unroll 4
    for (int r = 0; r < CHL; ++r) {
        const int row = rowbase + r;
        const float* brow = &sB[r * NSTATE];
        size_t o2 = (size_t)row * (2 * D_INNER) + d;
        float dl = delta[(size_t)row * D_INNER + d];
        float u  = bf2f(xcp[o2]) + bf2f(xcp[o2 + D_INNER]);
        float du = dl * u;
        #pragma unroll
        for (int n = 0; n < NSTATE; ++n) {
            float dA = __expf(dl * adn[n]);
            h[n] = fmaf(dA, h[n], du * brow[n]);
            P[n] *= dA;
        }
    }
    size_t base = (size_t)c * BDN + (size_t)(b * D_INNER + d) * NSTATE;
    #pragma unroll
    for (int k = 0; k < 4; ++k) {
        *(float4*)(hpart + base + k * 4) = make_float4(h[k*4], h[k*4+1], h[k*4+2], h[k*4+3]);
        *(float4*)(Pp    + base + k * 4) = make_float4(P[k*4], P[k*4+1], P[k*4+2], P[k*4+3]);
    }
}

/* scanB: hstart written IN PLACE over hpart (read hp/P before writing). */
__global__ __launch_bounds__(256) void scanB_kernel(
        float* __restrict__ hpart, const float* __restrict__ Pp) {
    int idx = blockIdx.x * 256 + threadIdx.x;
    float h = 0.f;
    for (int c = 0; c < NCH; ++c) {
        size_t o = (size_t)c * BDN + idx;
        float hp = hpart[o];
        float p  = Pp[o];
        hpart[o] = h;                 /* hstart for chunk c */
        h = fmaf(p, h, hp);
    }
}

/* scanC: y_p aliases xcp (in-place, per-cell exclusive ownership). */
__global__ __launch_bounds__(256) void scanC_kernel(
        const unsigned short* xcp, const float* __restrict__ delta,
        const float* __restrict__ xdbl, const float* __restrict__ A_log,
        const float* __restrict__ Dp, const float* __restrict__ hstart,
        const float* __restrict__ res, unsigned short* y_p) {
    __shared__ float sB[CHL * NSTATE];
    __shared__ float sC[CHL * NSTATE];
    const int bid = blockIdx.x;            /* 1024 blocks */
    const int b    = bid >> 9;
    const int c    = (bid >> 3) & 63;
    const int dblk = bid & 7;
    const int d    = (dblk << 8) + threadIdx.x;
    const int rowbase = b * SEQ + c * CHL;
    #pragma unroll
    for (int q = 0; q < 2; ++q) {
        int e = threadIdx.x + q * 256;
        int r = e >> 4, n = e & 15;
        sB[e] = xdbl[(size_t)(rowbase + r) * XDBL + DT_RANK + n];
        sC[e] = xdbl[(size_t)(rowbase + r) * XDBL + DT_RANK + NSTATE + n];
    }
    float adn[NSTATE];
    #pragma unroll
    for (int k = 0; k < 4; ++k) {
        float4 a = *(const float4*)(A_log + d * NSTATE + k * 4);
        adn[k*4+0] = -__expf(a.x); adn[k*4+1] = -__expf(a.y);
        adn[k*4+2] = -__expf(a.z); adn[k*4+3] = -__expf(a.w);
    }
    const float Dd = Dp[d];
    float h[NSTATE];
    size_t base = (size_t)c * BDN + (size_t)(b * D_INNER + d) * NSTATE;
    #pragma unroll
    for (int k = 0; k < 4; ++k) {
        float4 hv = *(const float4*)(hstart + base + k * 4);
        h[k*4] = hv.x; h[k*4+1] = hv.y; h[k*4+2] = hv.z; h[k*4+3] = hv.w;
    }
    __syncthreads();
    #pragma unroll 4
    for (int r = 0; r < CHL; ++r) {
        const int row = rowbase + r;
        const float* brow = &sB[r * NSTATE];
        const float* crow = &sC[r * NSTATE];
        size_t o2 = (size_t)row * (2 * D_INNER) + d;
        float dl = delta[(size_t)row * D_INNER + d];
        float u  = bf2f(xcp[o2]) + bf2f(xcp[o2 + D_INNER]);
        float du = dl * u;
        float ys[4];
        ys[0] = u * Dd; ys[1] = 0.f; ys[2] = 0.f; ys[3] = 0.f;
        #pragma unroll
        for (int n = 0; n < NSTATE; ++n) {
            float dA = __expf(dl * adn[n]);
            h[n] = fmaf(dA, h[n], du * brow[n]);
            ys[n & 3] = fmaf(h[n], crow[n], ys[n & 3]);
        }
        float ysum = (ys[0] + ys[1]) + (ys[2] + ys[3]);
        float rv = res[(size_t)row * D_INNER + d];
        float gv = ysum * silu_f(rv);
        unsigned short hi = f2bf(gv);
        unsigned short lo = f2bf(gv - bf2f(hi));
        y_p[o2]           = hi;
        y_p[o2 + D_INNER] = lo;
    }
}

extern "C" void kernel_launch(void* const* d_in, const int* in_sizes, int n_in,
                              void* d_out, int out_size, void* d_ws, size_t ws_size,
                              hipStream_t stream) {
    const float* x         = (const float*)d_in[0];
    const float* norm_w    = (const float*)d_in[1];
    const float* in_proj_w = (const float*)d_in[2];
    const float* conv_w    = (const float*)d_in[3];
    const float* conv_b    = (const float*)d_in[4];
    const float* x_proj_w  = (const float*)d_in[5];
    const float* dt_proj_w = (const float*)d_in[6];
    const float* dt_proj_b = (const float*)d_in[7];
    const float* A_log     = (const float*)d_in[8];
    const float* Dp        = (const float*)d_in[9];
    const float* out_proj_w= (const float*)d_in[10];
    float* out = (float*)d_out;
    float* ws  = (float*)d_ws;

    const size_t M8 = (size_t)T_TOK * D_INNER;           /* 8388608 */
    float* res   = ws;                                    /* 8M fl; dead after scanC */
    float* delta = res + M8;                              /* 8M fl; dead after scanC */
    float* xdbl  = delta + M8;                            /* 393216 fl */
    unsigned short* xn_p   = (unsigned short*)(xdbl + (size_t)T_TOK * XDBL);
    unsigned short* w_in_p = xn_p   + (size_t)4096 * 2048;   /* 4096x1024 sh */
    unsigned short* w_out_p= w_in_p + (size_t)4096 * 1024;   /* 1024x2048 sh */
    unsigned short* w_xp_p = w_out_p+ (size_t)1024 * 2048;   /* 96x4096 sh */
    unsigned short* w_dt_p = w_xp_p + (size_t)96 * 4096;     /* 2048x128 sh */
    unsigned short* xc_p   = w_dt_p + (size_t)2048 * 128;    /* 4096x4096 sh */
    unsigned short* dtp_p  = xc_p   + (size_t)4096 * 4096;   /* 4096x128 sh */
    float* xi    = (float*)(dtp_p + (size_t)4096 * 128);     /* 8M fl */
    float* hpart = xi;                          /* xi dead after conv; hstart in-place */
    float* Pp    = xi + (size_t)BDN * NCH;
    float* parts_x = delta;                     /* 8x524288 fl, pre-dt_proj */
    unsigned short* y_p = xc_p;                 /* in-place over packed xc */
    float* parts = ws;                          /* res+delta region: 16M fl (dead after scanC) */
    const size_t partStride = (size_t)T_TOK * HIDDEN;        /* 4194304 */

    /* merged weight packs: [hi], [hi], [hi|lo], [hi|lo] */
    wpack_all_kernel<<<6464, 256, 0, stream>>>(in_proj_w, w_in_p, out_proj_w, w_out_p,
                                               x_proj_w, w_xp_p, dt_proj_w, w_dt_p);

    /* RMSNorm + [hi|lo] pack */
    rmsnorm_pack_kernel<<<T_TOK, 256, 0, stream>>>(x, norm_w, xn_p);

    { /* in_proj (2-term, 128x256 tile): -> xi | res */
        dim3 g(4096 / 256, T_TOK / 128, 1);
        mgemm2_kernel<0><<<g, 256, 0, stream>>>(xn_p, 2 * HIDDEN, HIDDEN,
                                                w_in_p, HIDDEN, HIDDEN,
                                                xi, res, D_INNER, 0);
    }

    /* conv + SiLU -> [hi|lo] packed xc */
    conv_silu_kernel<<<(int)(M8 / 256), 256, 0, stream>>>(xi, conv_w, conv_b, xc_p);

    { /* x_proj (3-term, split-K=8, N padded 96->128): partials */
        dim3 g(1, T_TOK / 128, 8);
        mgemm_kernel<2><<<g, 256, 0, stream>>>(xc_p, w_xp_p, D_INNER, D_INNER / 8,
                                               96, parts_x, 128, 524288, nullptr);
    }
    reduceX_kernel<<<T_TOK * 24 / 256, 256, 0, stream>>>(parts_x, xdbl, dtp_p);

    { /* dt_proj (3-term) + bias + softplus -> delta */
        dim3 g(D_INNER / 128, T_TOK / 128, 1);
        mgemm_kernel<3><<<g, 256, 0, stream>>>(dtp_p, w_dt_p, DT_RANK, DT_RANK,
                                               D_INNER, delta, D_INNER, 0, dt_proj_b);
    }

    /* selective scan */
    scanA_kernel<<<BATCH * NCH * 8, 256, 0, stream>>>(xc_p, delta, xdbl, A_log, hpart, Pp);
    scanB_kernel<<<BDN / 256, 256, 0, stream>>>(hpart, Pp);
    scanC_kernel<<<BATCH * NCH * 8, 256, 0, stream>>>(xc_p, delta, xdbl, A_log, Dp,
                                                      hpart, res, y_p);

    { /* out_proj (2-term, 128x256 tile, split-K=4): partials */
        dim3 g(HIDDEN / 256, T_TOK / 128, 4);
        mgemm2_kernel<2><<<g, 256, 0, stream>>>(y_p, 2 * D_INNER, D_INNER,
                                                w_out_p, D_INNER, D_INNER / 4,
                                                parts, nullptr, HIDDEN, partStride);
    }
    /* residual + reduce */
    reduce4_kernel<<<(int)(partStride / 4 / 256), 256, 0, stream>>>(parts, partStride, x, out);
}

// Round 12
// 287.830 us; speedup vs baseline: 1.1068x; 1.0270x over previous
//
#include <hip/hip_runtime.h>
#include <math.h>

#define HIDDEN   1024
#define D_INNER  2048
#define NSTATE   16
#define DT_RANK  64
#define BATCH    2
#define SEQ      2048
#define T_TOK    (BATCH * SEQ)            /* 4096 tokens */
#define XDBL     (DT_RANK + 2 * NSTATE)   /* 96 */
#define NCH      64                       /* scan chunks */
#define CHL      (SEQ / NCH)              /* 32 steps per chunk */
#define BDN      (BATCH * D_INNER * NSTATE) /* 65536 */

typedef float f32x4   __attribute__((ext_vector_type(4)));
typedef short bf16x8  __attribute__((ext_vector_type(8)));
typedef short short4v __attribute__((ext_vector_type(4)));

#define AS1 __attribute__((address_space(1)))
#define AS3 __attribute__((address_space(3)))
#define GLOAD(src, dst) __builtin_amdgcn_global_load_lds( \
    (const AS1 unsigned int*)(src), (AS3 unsigned int*)(dst), 16, 0, 0)

__device__ __forceinline__ float silu_f(float x) { return x / (1.0f + __expf(-x)); }
__device__ __forceinline__ float softplus_f(float x) {
    return fmaxf(x, 0.0f) + log1pf(__expf(-fabsf(x)));
}
__device__ __forceinline__ unsigned short f2bf(float x) {
    unsigned int u = __float_as_uint(x);
    u += 0x7fffu + ((u >> 16) & 1u);           /* RNE */
    return (unsigned short)(u >> 16);
}
__device__ __forceinline__ float bf2f(unsigned short h) {
    return __uint_as_float(((unsigned int)h) << 16);
}

/* ---- merged weight pack + RMSNorm (one launch) ----
   blocks [0,6464): weight packs; [6464,10560): rmsnorm rows.            */
__device__ __forceinline__ void pack_seg(
        const float* __restrict__ w, unsigned short* __restrict__ wp,
        int K, int segs, int i) {
    int kq = K >> 2;
    int row = i / kq;
    int c = (i - row * kq) << 2;
    float4 v = *(const float4*)(w + (size_t)row * K + c);
    short4v hi, lo;
    hi.x = f2bf(v.x); hi.y = f2bf(v.y); hi.z = f2bf(v.z); hi.w = f2bf(v.w);
    lo.x = f2bf(v.x - bf2f(hi.x)); lo.y = f2bf(v.y - bf2f(hi.y));
    lo.z = f2bf(v.z - bf2f(hi.z)); lo.w = f2bf(v.w - bf2f(hi.w));
    size_t b0 = (size_t)row * (segs * K) + c;
    *(short4v*)(wp + b0) = hi;
    if (segs == 2) *(short4v*)(wp + b0 + K) = lo;
}

__global__ __launch_bounds__(256) void wpack_rms_kernel(
        const float* __restrict__ win,  unsigned short* __restrict__ pin,
        const float* __restrict__ wout, unsigned short* __restrict__ pout,
        const float* __restrict__ wx,   unsigned short* __restrict__ px,
        const float* __restrict__ wdt,  unsigned short* __restrict__ pdt,
        const float* __restrict__ x,    const float* __restrict__ nw,
        unsigned short* __restrict__ xn_p) {
    int bid = blockIdx.x;
    int t = threadIdx.x;
    if (bid < 4096) {                 /* in_proj [4096][1024] -> [hi] */
        pack_seg(win, pin, HIDDEN, 1, bid * 256 + t);
    } else if (bid < 6144) {          /* out_proj [1024][2048] -> [hi] */
        pack_seg(wout, pout, D_INNER, 1, (bid - 4096) * 256 + t);
    } else if (bid < 6336) {          /* x_proj [96][2048] -> [hi|lo] */
        pack_seg(wx, px, D_INNER, 2, (bid - 6144) * 256 + t);
    } else if (bid < 6464) {          /* dt_proj [2048][64] -> [hi|lo] */
        pack_seg(wdt, pdt, DT_RANK, 2, (bid - 6336) * 256 + t);
    } else {                          /* rmsnorm + [hi|lo] pack */
        int row = bid - 6464;
        float4 v = ((const float4*)(x + (size_t)row * HIDDEN))[t];
        float ss = v.x*v.x + v.y*v.y + v.z*v.z + v.w*v.w;
        #pragma unroll
        for (int off = 32; off; off >>= 1) ss += __shfl_down(ss, off);
        __shared__ float wsum[4];
        if ((t & 63) == 0) wsum[t >> 6] = ss;
        __syncthreads();
        float scale = rsqrtf((wsum[0] + wsum[1] + wsum[2] + wsum[3]) / (float)HIDDEN + 1e-5f);
        float4 wv = ((const float4*)nw)[t];
        float o0 = v.x * scale * wv.x, o1 = v.y * scale * wv.y;
        float o2 = v.z * scale * wv.z, o3 = v.w * scale * wv.w;
        short4v hi, lo;
        hi.x = f2bf(o0); hi.y = f2bf(o1); hi.z = f2bf(o2); hi.w = f2bf(o3);
        lo.x = f2bf(o0 - bf2f(hi.x)); lo.y = f2bf(o1 - bf2f(hi.y));
        lo.z = f2bf(o2 - bf2f(hi.z)); lo.w = f2bf(o3 - bf2f(hi.w));
        size_t b0 = (size_t)row * (2 * HIDDEN) + t * 4;
        *(short4v*)&xn_p[b0]          = hi;
        *(short4v*)&xn_p[b0 + HIDDEN] = lo;
    }
}

/* ---- 2-term GEMM, 128x256 tile, LDS 64KB, 2 blocks/CU ----
   C[M,N] = (Ah+Al)[M,Klog] @ Wh[N,Klog]^T  over k in [z*klen,(z+1)*klen)
   EPI 0 (in_proj): cols<2048 -> O0 packed [hi|lo] (row stride 4096);
                    cols>=2048 -> O1 single bf16 (row stride 2048).
   EPI 2 (out_proj): single-bf16 partial -> O0 + z*partStride (shorts). */
template<int EPI>
__global__ __launch_bounds__(256, 2) void mgemm2_kernel(
        const unsigned short* __restrict__ Ap, int Asr, int loOff,
        const unsigned short* __restrict__ Wp, int Wsr,
        int klen, unsigned short* __restrict__ O0, unsigned short* __restrict__ O1,
        int ldout, size_t partStride) {
    __shared__ short Ah[128 * 64];
    __shared__ short Al[128 * 64];
    __shared__ short Bh[256 * 64];
    const int t = threadIdx.x;
    const int w = t >> 6, l = t & 63;
    const int m0 = blockIdx.y * 128, n0 = blockIdx.x * 256;
    const int kbeg = blockIdx.z * klen;
    const int lrow = l & 15;
    f32x4 acc[8][4];
    #pragma unroll
    for (int m = 0; m < 8; ++m)
        #pragma unroll
        for (int n = 0; n < 4; ++n) {
            acc[m][n].x = 0.f; acc[m][n].y = 0.f; acc[m][n].z = 0.f; acc[m][n].w = 0.f;
        }
    const int srow8 = l >> 3;                       /* 0..7 */
    const int sc8   = (l & 7) ^ srow8;              /* pre-swizzled col8 */
    const unsigned short* ga = Ap + (size_t)(m0 + w * 32 + srow8) * Asr + sc8 * 8;
    const unsigned short* gb = Wp + (size_t)(n0 + w * 64 + srow8) * Wsr + sc8 * 8;
    for (int k0 = kbeg; k0 < kbeg + klen; k0 += 64) {
        __syncthreads();
        #pragma unroll
        for (int q = 0; q < 4; ++q) {
            const int ar = (w * 32 + q * 8) * 128;  /* byte offset */
            GLOAD(ga + k0 + (size_t)q * 8 * Asr,         (char*)Ah + ar);
            GLOAD(ga + loOff + k0 + (size_t)q * 8 * Asr, (char*)Al + ar);
        }
        #pragma unroll
        for (int q = 0; q < 8; ++q)
            GLOAD(gb + k0 + (size_t)q * 8 * Wsr, (char*)Bh + (w * 64 + q * 8) * 128);
        __syncthreads();
        #pragma unroll
        for (int kk = 0; kk < 2; ++kk) {
            const int slot = ((kk * 4 + (l >> 4)) ^ (l & 7)) * 8;
            bf16x8 bh[4];
            #pragma unroll
            for (int n = 0; n < 4; ++n)
                bh[n] = *(const bf16x8*)&Bh[(w * 64 + n * 16 + lrow) * 64 + slot];
            #pragma unroll
            for (int m = 0; m < 8; ++m) {
                bf16x8 ah = *(const bf16x8*)&Ah[(m * 16 + lrow) * 64 + slot];
                bf16x8 al = *(const bf16x8*)&Al[(m * 16 + lrow) * 64 + slot];
                #pragma unroll
                for (int n = 0; n < 4; ++n) {
                    acc[m][n] = __builtin_amdgcn_mfma_f32_16x16x32_bf16(
                        ah, bh[n], acc[m][n], 0, 0, 0);
                    acc[m][n] = __builtin_amdgcn_mfma_f32_16x16x32_bf16(
                        al, bh[n], acc[m][n], 0, 0, 0);
                }
            }
        }
    }
    #pragma unroll
    for (int m = 0; m < 8; ++m) {
        #pragma unroll
        for (int n = 0; n < 4; ++n) {
            #pragma unroll
            for (int j = 0; j < 4; ++j) {
                int row = m0 + m * 16 + (l >> 4) * 4 + j;
                int col = n0 + w * 64 + n * 16 + (l & 15);
                float v = acc[m][n][j];
                if (EPI == 0) {
                    if (col < D_INNER) {          /* xi side: [hi|lo] packed */
                        unsigned short hi = f2bf(v);
                        unsigned short lo = f2bf(v - bf2f(hi));
                        size_t o = (size_t)row * (2 * D_INNER) + col;
                        O0[o]           = hi;
                        O0[o + D_INNER] = lo;
                    } else {                      /* res side: single bf16 */
                        O1[(size_t)row * D_INNER + (col - D_INNER)] = f2bf(v);
                    }
                } else {                          /* bf16 partial */
                    O0[blockIdx.z * partStride + (size_t)row * ldout + col] = f2bf(v);
                }
            }
        }
    }
}

/* ---- component-packed 3-term split-bf16 GEMM (128x128) — x_proj / dt_proj ----
   C = Ah·Wh + Ah·Wl + Al·Wh  (A [hi|lo] stride 2K, W [hi|lo] stride 2K)
   EPI 2: fp32 partial store to C0 + z*partStride
   EPI 3: softplus(v + bias[col]) -> C0                                   */
template<int EPI>
__global__ __launch_bounds__(256) void mgemm_kernel(
        const unsigned short* __restrict__ Ap, const unsigned short* __restrict__ Wp,
        int Klog, int klen, int brows, float* __restrict__ C0,
        int ldout, size_t partStride, const float* __restrict__ bias) {
    __shared__ short lds[4 * 128 * 64];
    short* Ah = lds;
    short* Al = lds + 128 * 64;
    short* Bh = lds + 2 * 128 * 64;
    short* Bl = lds + 3 * 128 * 64;
    const int t = threadIdx.x;
    const int w = t >> 6, l = t & 63;
    const int m0 = blockIdx.y * 128, n0 = blockIdx.x * 128;
    const int kbeg = blockIdx.z * klen;
    const int wr = (w >> 1) * 64, wc = (w & 1) * 64;
    const int lrow = l & 15;
    f32x4 acc[4][4];
    #pragma unroll
    for (int m = 0; m < 4; ++m)
        #pragma unroll
        for (int n = 0; n < 4; ++n) {
            acc[m][n].x = 0.f; acc[m][n].y = 0.f; acc[m][n].z = 0.f; acc[m][n].w = 0.f;
        }
    const int Asr = 2 * Klog;
    const int Wsr = 2 * Klog;
    const int srow = w * 32 + (l >> 3);
    const int sc8  = (l & 7) ^ ((l >> 3) & 7);
    const int brow = min(n0 + srow, brows - 1);   /* clamp for padded-N */
    const unsigned short* ga = Ap + (size_t)(m0 + srow) * Asr + sc8 * 8;
    const unsigned short* gb = Wp + (size_t)brow * Wsr + sc8 * 8;
    for (int k0 = kbeg; k0 < kbeg + klen; k0 += 64) {
        __syncthreads();
        #pragma unroll
        for (int q = 0; q < 4; ++q) {
            const int doff = (w * 32 + q * 8) * 128;
            GLOAD(ga + k0 + (size_t)q * 8 * Asr,        (char*)Ah + doff);
            GLOAD(ga + Klog + k0 + (size_t)q * 8 * Asr, (char*)Al + doff);
            GLOAD(gb + k0 + (size_t)q * 8 * Wsr,        (char*)Bh + doff);
            GLOAD(gb + Klog + k0 + (size_t)q * 8 * Wsr, (char*)Bl + doff);
        }
        __syncthreads();
        #pragma unroll
        for (int kk = 0; kk < 2; ++kk) {
            const int slot = ((kk * 4 + (l >> 4)) ^ (l & 7)) * 8;
            bf16x8 ah[4], al[4], bh[4], bl[4];
            #pragma unroll
            for (int m = 0; m < 4; ++m) {
                ah[m] = *(const bf16x8*)&Ah[(wr + m * 16 + lrow) * 64 + slot];
                al[m] = *(const bf16x8*)&Al[(wr + m * 16 + lrow) * 64 + slot];
            }
            #pragma unroll
            for (int n = 0; n < 4; ++n) {
                bh[n] = *(const bf16x8*)&Bh[(wc + n * 16 + lrow) * 64 + slot];
                bl[n] = *(const bf16x8*)&Bl[(wc + n * 16 + lrow) * 64 + slot];
            }
            #pragma unroll
            for (int m = 0; m < 4; ++m)
                #pragma unroll
                for (int n = 0; n < 4; ++n) {
                    acc[m][n] = __builtin_amdgcn_mfma_f32_16x16x32_bf16(
                        ah[m], bh[n], acc[m][n], 0, 0, 0);
                    acc[m][n] = __builtin_amdgcn_mfma_f32_16x16x32_bf16(
                        al[m], bh[n], acc[m][n], 0, 0, 0);
                    acc[m][n] = __builtin_amdgcn_mfma_f32_16x16x32_bf16(
                        ah[m], bl[n], acc[m][n], 0, 0, 0);
                }
        }
    }
    float* dst = (EPI == 2) ? (C0 + blockIdx.z * partStride) : C0;
    #pragma unroll
    for (int m = 0; m < 4; ++m) {
        #pragma unroll
        for (int n = 0; n < 4; ++n) {
            #pragma unroll
            for (int j = 0; j < 4; ++j) {
                int row = m0 + wr + m * 16 + (l >> 4) * 4 + j;
                int col = n0 + wc + n * 16 + (l & 15);
                float v = acc[m][n][j];
                if (EPI == 2) {
                    dst[(size_t)row * ldout + col] = v;
                } else {
                    C0[(size_t)row * ldout + col] = softplus_f(v + bias[col]);
                }
            }
        }
    }
}

/* ---- reduce 4 bf16 split-K partials + residual x -> out (out_proj) ---- */
__global__ __launch_bounds__(256) void reduce4_kernel(
        const unsigned short* __restrict__ parts, size_t partStride,
        const float* __restrict__ x, float* __restrict__ out) {
    size_t i = (size_t)blockIdx.x * 256 + threadIdx.x;   /* group of 4 outputs */
    short4v a = *(const short4v*)(parts + i * 4);
    short4v b = *(const short4v*)(parts + partStride + i * 4);
    short4v c = *(const short4v*)(parts + 2 * partStride + i * 4);
    short4v d = *(const short4v*)(parts + 3 * partStride + i * 4);
    float4 xv = ((const float4*)x)[i];
    float4 o;
    o.x = bf2f(a.x) + bf2f(b.x) + bf2f(c.x) + bf2f(d.x) + xv.x;
    o.y = bf2f(a.y) + bf2f(b.y) + bf2f(c.y) + bf2f(d.y) + xv.y;
    o.z = bf2f(a.z) + bf2f(b.z) + bf2f(c.z) + bf2f(d.z) + xv.z;
    o.w = bf2f(a.w) + bf2f(b.w) + bf2f(c.w) + bf2f(d.w) + xv.w;
    ((float4*)out)[i] = o;
}

/* ---- reduce 8 x_proj partials -> xdbl fp32 [4096,96] + dtp_p [hi|lo] [4096,128] ---- */
__global__ __launch_bounds__(256) void reduceX_kernel(
        const float* __restrict__ parts, float* __restrict__ xdbl,
        unsigned short* __restrict__ dtp) {
    int i = blockIdx.x * 256 + threadIdx.x;      /* 4096*24 total */
    int row = i / 24;
    int c = (i - row * 24) * 4;
    float4 s = make_float4(0.f, 0.f, 0.f, 0.f);
    #pragma unroll
    for (int z = 0; z < 8; ++z) {
        float4 a = *(const float4*)(parts + (size_t)z * 524288 + (size_t)row * 128 + c);
        s.x += a.x; s.y += a.y; s.z += a.z; s.w += a.w;
    }
    *(float4*)(xdbl + (size_t)row * XDBL + c) = s;
    if (c < DT_RANK) {
        short4v hi, lo;
        hi.x = f2bf(s.x); hi.y = f2bf(s.y); hi.z = f2bf(s.z); hi.w = f2bf(s.w);
        lo.x = f2bf(s.x - bf2f(hi.x)); lo.y = f2bf(s.y - bf2f(hi.y));
        lo.z = f2bf(s.z - bf2f(hi.z)); lo.w = f2bf(s.w - bf2f(hi.w));
        size_t b0 = (size_t)row * 128 + c;
        *(short4v*)(dtp + b0)      = hi;
        *(short4v*)(dtp + b0 + 64) = lo;
    }
}

/* ---- causal depthwise conv (d_conv=4) + SiLU: packed xi -> packed xc ---- */
__global__ __launch_bounds__(256) void conv_silu_kernel(
        const unsigned short* __restrict__ xi_p, const float* __restrict__ w,
        const float* __restrict__ b, unsigned short* __restrict__ xc_p) {
    size_t i = (size_t)blockIdx.x * 256 + threadIdx.x;   /* over T_TOK*D_INNER */
    int d = (int)(i & (D_INNER - 1));
    int tt = (int)(i >> 11);
    int s = tt & (SEQ - 1);
    float4 wv = ((const float4*)w)[d];
    float acc = b[d];
    #pragma unroll
    for (int k = 3; k >= 1; --k) {
        if (s >= k) {
            size_t o = (size_t)(tt - k) * (2 * D_INNER) + d;
            float u = bf2f(xi_p[o]) + bf2f(xi_p[o + D_INNER]);
            acc += ((const float*)&wv)[3 - k] * u;
        }
    }
    {
        size_t o = (size_t)tt * (2 * D_INNER) + d;
        float u = bf2f(xi_p[o]) + bf2f(xi_p[o + D_INNER]);
        acc += wv.w * u;
    }
    float o = silu_f(acc);
    unsigned short hi = f2bf(o);
    unsigned short lo = f2bf(o - bf2f(hi));
    size_t o2 = (size_t)tt * (2 * D_INNER) + d;
    xc_p[o2]           = hi;
    xc_p[o2 + D_INNER] = lo;
}

/* ==== selective scan: thread-per-(b,d,chunk), states in registers.
   B/C rows staged in LDS once per chunk (uniform-read broadcast).   ==== */

__global__ __launch_bounds__(256) void scanA_kernel(
        const unsigned short* __restrict__ xcp, const float* __restrict__ delta,
        const float* __restrict__ xdbl, const float* __restrict__ A_log,
        float* __restrict__ hpart, float* __restrict__ Pp) {
    __shared__ float sB[CHL * NSTATE];
    const int bid = blockIdx.x;            /* 1024 blocks */
    const int b    = bid >> 9;
    const int c    = (bid >> 3) & 63;
    const int dblk = bid & 7;
    const int d    = (dblk << 8) + threadIdx.x;
    const int rowbase = b * SEQ + c * CHL;
    #pragma unroll
    for (int q = 0; q < 2; ++q) {
        int e = threadIdx.x + q * 256;
        int r = e >> 4, n = e & 15;
        sB[e] = xdbl[(size_t)(rowbase + r) * XDBL + DT_RANK + n];
    }
    float adn[NSTATE];
    #pragma unroll
    for (int k = 0; k < 4; ++k) {
        float4 a = *(const float4*)(A_log + d * NSTATE + k * 4);
        adn[k*4+0] = -__expf(a.x); adn[k*4+1] = -__expf(a.y);
        adn[k*4+2] = -__expf(a.z); adn[k*4+3] = -__expf(a.w);
    }
    float h[NSTATE], P[NSTATE];
    #pragma unroll
    for (int n = 0; n < NSTATE; ++n) { h[n] = 0.f; P[n] = 1.f; }
    __syncthreads();
    #pragma unroll 4
    for (int r = 0; r < CHL; ++r) {
        const int row = rowbase + r;
        const float* brow = &sB[r * NSTATE];
        size_t o2 = (size_t)row * (2 * D_INNER) + d;
        float dl = delta[(size_t)row * D_INNER + d];
        float u  = bf2f(xcp[o2]) + bf2f(xcp[o2 + D_INNER]);
        float du = dl * u;
        #pragma unroll
        for (int n = 0; n < NSTATE; ++n) {
            float dA = __expf(dl * adn[n]);
            h[n] = fmaf(dA, h[n], du * brow[n]);
            P[n] *= dA;
        }
    }
    size_t base = (size_t)c * BDN + (size_t)(b * D_INNER + d) * NSTATE;
    #pragma unroll
    for (int k = 0; k < 4; ++k) {
        *(float4*)(hpart + base + k * 4) = make_float4(h[k*4], h[k*4+1], h[k*4+2], h[k*4+3]);
        *(float4*)(Pp    + base + k * 4) = make_float4(P[k*4], P[k*4+1], P[k*4+2], P[k*4+3]);
    }
}

/* scanB: hstart written IN PLACE over hpart (read hp/P before writing). */
__global__ __launch_bounds__(256) void scanB_kernel(
        float* __restrict__ hpart, const float* __restrict__ Pp) {
    int idx = blockIdx.x * 256 + threadIdx.x;
    float h = 0.f;
    for (int c = 0; c < NCH; ++c) {
        size_t o = (size_t)c * BDN + idx;
        float hp = hpart[o];
        float p  = Pp[o];
        hpart[o] = h;                 /* hstart for chunk c */
        h = fmaf(p, h, hp);
    }
}

/* scanC: y_p aliases xcp (in-place, per-cell exclusive ownership);
   res is single bf16.                                                  */
__global__ __launch_bounds__(256) void scanC_kernel(
        const unsigned short* xcp, const float* __restrict__ delta,
        const float* __restrict__ xdbl, const float* __restrict__ A_log,
        const float* __restrict__ Dp, const float* __restrict__ hstart,
        const unsigned short* __restrict__ res_b, unsigned short* y_p) {
    __shared__ float sB[CHL * NSTATE];
    __shared__ float sC[CHL * NSTATE];
    const int bid = blockIdx.x;            /* 1024 blocks */
    const int b    = bid >> 9;
    const int c    = (bid >> 3) & 63;
    const int dblk = bid & 7;
    const int d    = (dblk << 8) + threadIdx.x;
    const int rowbase = b * SEQ + c * CHL;
    #pragma unroll
    for (int q = 0; q < 2; ++q) {
        int e = threadIdx.x + q * 256;
        int r = e >> 4, n = e & 15;
        sB[e] = xdbl[(size_t)(rowbase + r) * XDBL + DT_RANK + n];
        sC[e] = xdbl[(size_t)(rowbase + r) * XDBL + DT_RANK + NSTATE + n];
    }
    float adn[NSTATE];
    #pragma unroll
    for (int k = 0; k < 4; ++k) {
        float4 a = *(const float4*)(A_log + d * NSTATE + k * 4);
        adn[k*4+0] = -__expf(a.x); adn[k*4+1] = -__expf(a.y);
        adn[k*4+2] = -__expf(a.z); adn[k*4+3] = -__expf(a.w);
    }
    const float Dd = Dp[d];
    float h[NSTATE];
    size_t base = (size_t)c * BDN + (size_t)(b * D_INNER + d) * NSTATE;
    #pragma unroll
    for (int k = 0; k < 4; ++k) {
        float4 hv = *(const float4*)(hstart + base + k * 4);
        h[k*4] = hv.x; h[k*4+1] = hv.y; h[k*4+2] = hv.z; h[k*4+3] = hv.w;
    }
    __syncthreads();
    #pragma unroll 4
    for (int r = 0; r < CHL; ++r) {
        const int row = rowbase + r;
        const float* brow = &sB[r * NSTATE];
        const float* crow = &sC[r * NSTATE];
        size_t o2 = (size_t)row * (2 * D_INNER) + d;
        float dl = delta[(size_t)row * D_INNER + d];
        float u  = bf2f(xcp[o2]) + bf2f(xcp[o2 + D_INNER]);
        float du = dl * u;
        float ys[4];
        ys[0] = u * Dd; ys[1] = 0.f; ys[2] = 0.f; ys[3] = 0.f;
        #pragma unroll
        for (int n = 0; n < NSTATE; ++n) {
            float dA = __expf(dl * adn[n]);
            h[n] = fmaf(dA, h[n], du * brow[n]);
            ys[n & 3] = fmaf(h[n], crow[n], ys[n & 3]);
        }
        float ysum = (ys[0] + ys[1]) + (ys[2] + ys[3]);
        float rv = bf2f(res_b[(size_t)row * D_INNER + d]);
        float gv = ysum * silu_f(rv);
        unsigned short hi = f2bf(gv);
        unsigned short lo = f2bf(gv - bf2f(hi));
        y_p[o2]           = hi;
        y_p[o2 + D_INNER] = lo;
    }
}

extern "C" void kernel_launch(void* const* d_in, const int* in_sizes, int n_in,
                              void* d_out, int out_size, void* d_ws, size_t ws_size,
                              hipStream_t stream) {
    const float* x         = (const float*)d_in[0];
    const float* norm_w    = (const float*)d_in[1];
    const float* in_proj_w = (const float*)d_in[2];
    const float* conv_w    = (const float*)d_in[3];
    const float* conv_b    = (const float*)d_in[4];
    const float* x_proj_w  = (const float*)d_in[5];
    const float* dt_proj_w = (const float*)d_in[6];
    const float* dt_proj_b = (const float*)d_in[7];
    const float* A_log     = (const float*)d_in[8];
    const float* Dp        = (const float*)d_in[9];
    const float* out_proj_w= (const float*)d_in[10];
    float* out = (float*)d_out;
    float* ws  = (float*)d_ws;

    const size_t M8 = (size_t)T_TOK * D_INNER;           /* 8388608 */
    /* [0,8M fl): res_b (16M sh, first half) — dead after scanC;
                  parts_b (out_proj bf16 partials, 16M sh) aliases after */
    unsigned short* res_b  = (unsigned short*)ws;
    unsigned short* parts_b= (unsigned short*)ws;
    float* delta = ws + M8;                               /* 8M fl */
    float* xdbl  = delta + M8;                            /* 393216 fl */
    unsigned short* xn_p   = (unsigned short*)(xdbl + (size_t)T_TOK * XDBL);
    unsigned short* w_in_p = xn_p   + (size_t)4096 * 2048;   /* 4096x1024 sh */
    unsigned short* w_out_p= w_in_p + (size_t)4096 * 1024;   /* 1024x2048 sh */
    unsigned short* w_xp_p = w_out_p+ (size_t)1024 * 2048;   /* 96x4096 sh */
    unsigned short* w_dt_p = w_xp_p + (size_t)96 * 4096;     /* 2048x128 sh */
    unsigned short* xc_p   = w_dt_p + (size_t)2048 * 128;    /* 4096x4096 sh */
    unsigned short* dtp_p  = xc_p   + (size_t)4096 * 4096;   /* 4096x128 sh */
    unsigned short* xi_p   = dtp_p + (size_t)4096 * 128;     /* 4096x4096 sh */
    float* hpart = (float*)xi_p;                /* xi dead after conv; hstart in-place */
    float* Pp    = hpart + (size_t)BDN * NCH;
    float* parts_x = delta;                     /* 8x524288 fl, pre-dt_proj */
    unsigned short* y_p = xc_p;                 /* in-place over packed xc */
    const size_t partStride = (size_t)T_TOK * HIDDEN;        /* 4194304 shorts */

    /* merged weight packs + rmsnorm */
    wpack_rms_kernel<<<6464 + T_TOK, 256, 0, stream>>>(
        in_proj_w, w_in_p, out_proj_w, w_out_p, x_proj_w, w_xp_p,
        dt_proj_w, w_dt_p, x, norm_w, xn_p);

    { /* in_proj (2-term, 128x256 tile): -> xi_p [hi|lo] | res_b bf16 */
        dim3 g(4096 / 256, T_TOK / 128, 1);
        mgemm2_kernel<0><<<g, 256, 0, stream>>>(xn_p, 2 * HIDDEN, HIDDEN,
                                                w_in_p, HIDDEN, HIDDEN,
                                                xi_p, res_b, 0, 0);
    }

    /* conv + SiLU: packed xi -> packed xc */
    conv_silu_kernel<<<(int)(M8 / 256), 256, 0, stream>>>(xi_p, conv_w, conv_b, xc_p);

    { /* x_proj (3-term, split-K=8, N padded 96->128): fp32 partials */
        dim3 g(1, T_TOK / 128, 8);
        mgemm_kernel<2><<<g, 256, 0, stream>>>(xc_p, w_xp_p, D_INNER, D_INNER / 8,
                                               96, parts_x, 128, 524288, nullptr);
    }
    reduceX_kernel<<<T_TOK * 24 / 256, 256, 0, stream>>>(parts_x, xdbl, dtp_p);

    { /* dt_proj (3-term) + bias + softplus -> delta */
        dim3 g(D_INNER / 128, T_TOK / 128, 1);
        mgemm_kernel<3><<<g, 256, 0, stream>>>(dtp_p, w_dt_p, DT_RANK, DT_RANK,
                                               D_INNER, delta, D_INNER, 0, dt_proj_b);
    }

    /* selective scan */
    scanA_kernel<<<BATCH * NCH * 8, 256, 0, stream>>>(xc_p, delta, xdbl, A_log, hpart, Pp);
    scanB_kernel<<<BDN / 256, 256, 0, stream>>>(hpart, Pp);
    scanC_kernel<<<BATCH * NCH * 8, 256, 0, stream>>>(xc_p, delta, xdbl, A_log, Dp,
                                                      hpart, res_b, y_p);

    { /* out_proj (2-term, 128x256 tile, split-K=4): bf16 partials */
        dim3 g(HIDDEN / 256, T_TOK / 128, 4);
        mgemm2_kernel<2><<<g, 256, 0, stream>>>(y_p, 2 * D_INNER, D_INNER,
                                                w_out_p, D_INNER, D_INNER / 4,
                                                parts_b, nullptr, HIDDEN, partStride);
    }
    /* residual + bf16 reduce */
    reduce4_kernel<<<(int)(partStride / 4 / 256), 256, 0, stream>>>(parts_b, partStride, x, out);
}